// Round 9
// baseline (255.926 us; speedup 1.0000x reference)
//
#include <hip/hip_runtime.h>

#define BUFSZ 10000000
#define RESF 0.3f
// XLA canonicalizes x / const -> x * (1/const); 1.0f/0.3f folds to 0x40555555.
#define RINV (1.0f / 0.3f)

// ---- binning geometry -----------------------------------------------------
#define BIN_SHIFT   13
#define BKT_PER_BIN 8192                   // buckets per bin (32 KB LDS table)
#define NBINS       1221                   // ceil(10M / 8192)
#define BIN_CAP     2048                   // slots/bin (mean 1638, +10 sigma)
#define OVF_CAP     16384

// ---- ws layout (~50.2 MB; ws proven >= 112 MB) ----------------------------
#define E64_OFF  0ull                      // u64 [NBINS*BIN_CAP]  = 20.0 MB
#define EPOS_OFF 20004864ull               // f32 [3*NBINS*BIN_CAP]= 30.0 MB
#define CTL_OFF  50012160ull               // u32 [NBINS+1]
#define OVFA_OFF (CTL_OFF + 8192ull)       // u64 [OVF_CAP]
#define OVFB_OFF (OVFA_OFF + 131072ull)    // u32 [OVF_CAP]
#define WS_NEED  (OVFB_OFF + 65536ull)

// ---------------------------------------------------------------------------
// Shared per-point voxel math — bit-identical to the R3..R8 passing kernels.
// ---------------------------------------------------------------------------
__device__ __forceinline__ void voxel_hash_d(float px, float py, float pz,
                                             int& hw, unsigned& dbits)
{
#pragma clang fp contract(off)
    float fx = floorf(px * RINV);
    float fy = floorf(py * RINV);
    float fz = floorf(pz * RINV);

    long long gx = (long long)fx;
    long long gy = (long long)fy;
    long long gz = (long long)fz;
    long long s = gx * 73856093LL + gy * 19349669LL + gz * 83492791LL;
    long long h = s % (long long)BUFSZ;           // trunc, sign of dividend
    hw = (int)(h < 0 ? h + BUFSZ : h);

    float cx = (fx + 0.5f) * RESF;
    float cy = (fy + 0.5f) * RESF;
    float cz = (fz + 0.5f) * RESF;
    float dx = px - cx;
    float dy = py - cy;
    float dz = pz - cz;
    float d = dx * dx + dy * dy + dz * dz;        // no fp contraction
    dbits = __float_as_uint(d);
}

// ===========================================================================
// K1: multisplit binning, carrying point identity+position through.
// entry e64 = dbits(30) << 34 | pidx(21) << 13 | lbkt(13); epos = {px,py,pz}.
// dbits >= 2^30 (impossible for this input, exactness-guarded) and capacity
// overflow go to ovf (folded exactly into bin mins + output in K2).
// ===========================================================================
__global__ __launch_bounds__(256) void bin_points2(
    const float* __restrict__ points,
    unsigned long long* __restrict__ e64,
    float* __restrict__ epos,
    unsigned int* __restrict__ ctl,
    unsigned long long* __restrict__ ovfA,
    unsigned int* __restrict__ ovfB,
    int N)
{
    __shared__ unsigned int cnt[NBINS];
    int t = threadIdx.x;
    for (int b = t; b < NBINS; b += 256) cnt[b] = 0;
    __syncthreads();

    int base = blockIdx.x * (256 * 16);
    unsigned hwv[16];
    unsigned dbv[16];

#pragma unroll
    for (int k = 0; k < 16; ++k) {
        int i = base + t + k * 256;
        hwv[k] = 0xFFFFFFFFu;                      // sentinel: invalid
        dbv[k] = 0;
        if (i < N) {
            int hw; unsigned db;
            voxel_hash_d(points[3 * i], points[3 * i + 1], points[3 * i + 2],
                         hw, db);
            hwv[k] = (unsigned)hw;
            dbv[k] = db;
            if (db <= 0x3FFFFFFFu)
                atomicAdd(&cnt[hw >> BIN_SHIFT], 1u);
        }
    }
    __syncthreads();

    // reserve global ranges; cnt[b] becomes the block's running global cursor
    for (int b = t; b < NBINS; b += 256) {
        unsigned c = cnt[b];
        cnt[b] = c ? atomicAdd(&ctl[b], c) : 0u;
    }
    __syncthreads();

#pragma unroll
    for (int k = 0; k < 16; ++k) {
        if (hwv[k] == 0xFFFFFFFFu) continue;
        int i = base + t + k * 256;
        unsigned hw = hwv[k], db = dbv[k];
        if (db <= 0x3FFFFFFFu) {
            unsigned bin = hw >> BIN_SHIFT;
            unsigned idx = atomicAdd(&cnt[bin], 1u);
            if (idx < BIN_CAP) {
                size_t slot = (size_t)bin * BIN_CAP + idx;
                e64[slot] = ((unsigned long long)db << 34)
                          | ((unsigned long long)(unsigned)i << 13)
                          | (hw & (BKT_PER_BIN - 1));
                epos[3 * slot + 0] = points[3 * i + 0];   // L1-hot re-read
                epos[3 * slot + 1] = points[3 * i + 1];
                epos[3 * slot + 2] = points[3 * i + 2];
                continue;
            }
        }
        unsigned o = atomicAdd(&ctl[NBINS], 1u);
        if (o < OVF_CAP) {
            ovfA[o] = ((unsigned long long)db << 24) | hw;   // hw < 2^24
            ovfB[o] = (unsigned)i;
        }
    }
}

// ===========================================================================
// K2: per-bin LDS segment-min + full output computation.
//   tbl min <- regular entries + matching ovf entries (exactness)
//   keep: exact u32 compare; bufidx confined to the bin's 32KB window (L2-hot)
//   one random gather (neural + ts), outputs scattered by pidx.
// ===========================================================================
__global__ __launch_bounds__(256) void min_out(
    const unsigned long long* __restrict__ e64,
    const float* __restrict__ epos,
    const unsigned int* __restrict__ ctl,
    const unsigned long long* __restrict__ ovfA,
    const unsigned int* __restrict__ ovfB,
    const int* __restrict__ bufidx,
    const float* __restrict__ neural,
    const int* __restrict__ ts_upd,
    const float* __restrict__ travel,
    const int* __restrict__ cur_ts_p,
    const float* __restrict__ points,
    float* __restrict__ out,
    int N, int M)
{
#pragma clang fp contract(off)
    __shared__ unsigned int tbl[BKT_PER_BIN];      // 32 KB
    int t = threadIdx.x;
    int b = blockIdx.x;

    uint4* t4 = (uint4*)tbl;
    for (int l = t; l < BKT_PER_BIN / 4; l += 256)
        t4[l] = make_uint4(0xFFFFFFFFu, 0xFFFFFFFFu, 0xFFFFFFFFu, 0xFFFFFFFFu);
    __syncthreads();

    unsigned c = ctl[b];
    if (c > BIN_CAP) c = BIN_CAP;                  // excess went to ovf
    size_t ebase = (size_t)b * BIN_CAP;
    for (unsigned j = t; j < c; j += 256) {
        unsigned long long v = e64[ebase + j];
        atomicMin(&tbl[(unsigned)(v & (BKT_PER_BIN - 1))],
                  (unsigned)(v >> 34));
    }

    unsigned ovfn = ctl[NBINS];
    if (ovfn > OVF_CAP) ovfn = OVF_CAP;
    unsigned gbase = (unsigned)b << BIN_SHIFT;
    for (unsigned o = t; o < ovfn; o += 256) {     // statistically empty
        unsigned long long va = ovfA[o];
        unsigned hw = (unsigned)(va & 0xFFFFFFu);
        if ((hw >> BIN_SHIFT) == (unsigned)b)
            atomicMin(&tbl[hw & (BKT_PER_BIN - 1)], (unsigned)(va >> 24));
    }
    __syncthreads();

    float tcur = travel[cur_ts_p[0]];
    const float THR = (float)(3.0 * 0.3 * 0.3);

    for (unsigned j = t; j < c; j += 256) {
        unsigned long long v = e64[ebase + j];
        unsigned lb   = (unsigned)(v & (BKT_PER_BIN - 1));
        int      pidx = (int)((v >> 13) & 0x1FFFFFu);
        unsigned db   = (unsigned)(v >> 34);

        bool keep = db <= tbl[lb];

        int hidx = bufidx[gbase + lb];             // 32KB window -> L2-hot
        int idxw = (hidx < 0) ? (hidx + M) : hidx;

        float px = epos[3 * (ebase + j) + 0];
        float py = epos[3 * (ebase + j) + 1];
        float pz = epos[3 * (ebase + j) + 2];

        float vx = neural[3 * idxw + 0] - px;      // the one random gather
        float vy = neural[3 * idxw + 1] - py;
        float vz = neural[3 * idxw + 2] - pz;
        float dist2 = vx * vx + vy * vy + vz * vz; // no contraction

        int ts = ts_upd[idxw];                     // 8MB table, L2-cached
        float dtv = tcur - travel[ts];

        bool upd = keep && ((hidx == -1) || (dist2 > THR) || (dtv > 120.0f));

        out[pidx]         = dist2;
        out[N + pidx]     = dtv;
        out[2 * N + pidx] = upd ? 1.0f : 0.0f;
    }

    // ovf outputs (statistically none) — same math, pos re-read from points
    for (unsigned o = t; o < ovfn; o += 256) {
        unsigned long long va = ovfA[o];
        unsigned hw = (unsigned)(va & 0xFFFFFFu);
        if ((hw >> BIN_SHIFT) != (unsigned)b) continue;
        unsigned db = (unsigned)(va >> 24);
        int pidx = (int)ovfB[o];

        bool keep = db <= tbl[hw & (BKT_PER_BIN - 1)];

        int hidx = bufidx[hw];
        int idxw = (hidx < 0) ? (hidx + M) : hidx;

        float px = points[3 * pidx + 0];
        float py = points[3 * pidx + 1];
        float pz = points[3 * pidx + 2];

        float vx = neural[3 * idxw + 0] - px;
        float vy = neural[3 * idxw + 1] - py;
        float vz = neural[3 * idxw + 2] - pz;
        float dist2 = vx * vx + vy * vy + vz * vz;

        int ts = ts_upd[idxw];
        float dtv = tcur - travel[ts];

        bool upd = keep && ((hidx == -1) || (dist2 > THR) || (dtv > 120.0f));

        out[pidx]         = dist2;
        out[N + pidx]     = dtv;
        out[2 * N + pidx] = upd ? 1.0f : 0.0f;
    }
}

// ===========================================================================
// Tier C fallback (proven in R3): used only if ws/N don't fit the fast path.
// ===========================================================================
__global__ __launch_bounds__(256) void pass_min_C(
    const float* __restrict__ points, unsigned int* __restrict__ seg, int N)
{
    int i = blockIdx.x * 256 + threadIdx.x;
    if (i >= N) return;
    int hw; unsigned dbits;
    voxel_hash_d(points[3 * i], points[3 * i + 1], points[3 * i + 2], hw, dbits);
    atomicMin(seg + hw, dbits);
}

__global__ __launch_bounds__(256) void pass_out_C(
    const float* __restrict__ points, const float* __restrict__ neural,
    const int* __restrict__ bufidx, const float* __restrict__ travel,
    const int* __restrict__ ts_upd, const int* __restrict__ cur_ts_p,
    const unsigned int* __restrict__ seg, float* __restrict__ out, int N, int M)
{
#pragma clang fp contract(off)
    int i = blockIdx.x * 256 + threadIdx.x;
    if (i >= N) return;
    float px = points[3 * i], py = points[3 * i + 1], pz = points[3 * i + 2];
    int hw; unsigned dbits;
    voxel_hash_d(px, py, pz, hw, dbits);
    bool keep = dbits <= seg[hw];
    int hidx = bufidx[hw];
    int idxw = (hidx < 0) ? (hidx + M) : hidx;
    float vx = neural[3 * idxw] - px;
    float vy = neural[3 * idxw + 1] - py;
    float vz = neural[3 * idxw + 2] - pz;
    float dist2 = vx * vx + vy * vy + vz * vz;
    int ts = ts_upd[idxw];
    float dtv = travel[cur_ts_p[0]] - travel[ts];
    const float THR = (float)(3.0 * 0.3 * 0.3);
    bool upd = keep && ((hidx == -1) || (dist2 > THR) || (dtv > 120.0f));
    out[i] = dist2;
    out[N + i] = dtv;
    out[2 * N + i] = upd ? 1.0f : 0.0f;
}

extern "C" void kernel_launch(void* const* d_in, const int* in_sizes, int n_in,
                              void* d_out, int out_size, void* d_ws, size_t ws_size,
                              hipStream_t stream)
{
    const float* points  = (const float*)d_in[0];
    const float* neural  = (const float*)d_in[1];
    const int*   bufidx  = (const int*)d_in[2];
    const float* travel  = (const float*)d_in[3];
    const int*   ts_upd  = (const int*)d_in[4];
    const int*   cur_ts  = (const int*)d_in[5];

    int N = in_sizes[0] / 3;
    int M = in_sizes[1] / 3;

    if (ws_size >= WS_NEED && N <= (1 << 21)) {
        char* ws = (char*)d_ws;
        unsigned long long* e64  = (unsigned long long*)(ws + E64_OFF);
        float*              epos = (float*)(ws + EPOS_OFF);
        unsigned int*       ctl  = (unsigned int*)(ws + CTL_OFF);
        unsigned long long* ovfA = (unsigned long long*)(ws + OVFA_OFF);
        unsigned int*       ovfB = (unsigned int*)(ws + OVFB_OFF);

        hipMemsetAsync(ctl, 0, 8192, stream);

        int bblocks = (N + 4095) / 4096;
        bin_points2<<<bblocks, 256, 0, stream>>>(points, e64, epos, ctl,
                                                 ovfA, ovfB, N);
        min_out<<<NBINS, 256, 0, stream>>>(e64, epos, ctl, ovfA, ovfB,
                                           bufidx, neural, ts_upd, travel,
                                           cur_ts, points, (float*)d_out, N, M);
    } else {
        unsigned int* seg = (unsigned int*)d_ws;               // 40 MB
        hipMemsetAsync(seg, 0xFF, (size_t)BUFSZ * sizeof(unsigned int), stream);
        int pblocks = (N + 255) / 256;
        pass_min_C<<<pblocks, 256, 0, stream>>>(points, seg, N);
        pass_out_C<<<pblocks, 256, 0, stream>>>(points, neural, bufidx, travel,
                                                ts_upd, cur_ts, seg,
                                                (float*)d_out, N, M);
    }
}

// Round 10
// 161.480 us; speedup vs baseline: 1.5849x; 1.5849x over previous
//
#include <hip/hip_runtime.h>

#define BUFSZ 10000000
#define RESF 0.3f
// XLA canonicalizes x / const -> x * (1/const); 1.0f/0.3f folds to 0x40555555.
#define RINV (1.0f / 0.3f)

// ---- binning geometry -----------------------------------------------------
#define BIN_SHIFT   13
#define BKT_PER_BIN 8192                     // buckets per bin (32 KB LDS table)
#define NBINS       1221                     // ceil(10M / 8192)
#define BIN_CAP     2048                     // slots/bin (mean 1638, +10 sigma)
#define OVF_CAP     16384

// ---- scratch layout -------------------------------------------------------
// ws (proven >= 112 MB):
//   [0, 80M)    p8   uint2[10M] {min_bits, bufidx}
//   [80M,112M)  pnt  float4[2M] {x,y,z,ts}
// d_out used as scratch (24 MB, fully rewritten by pass_out_A4):
//   [0, 20.00M)          e64  u64[NBINS*BIN_CAP]
//   [20,004,864, +8KB)   ctl  u32[NBINS] counts + [NBINS] = ovf count
//   [20,013,056, +128KB) ovf  u64[OVF_CAP]
#define PNT_WS_OFF  80000000ull
#define E64_OUT_OFF 0ull
#define CTL_OUT_OFF 20004864ull
#define OVF_OUT_OFF 20013056ull
#define OUT_NEED    (OVF_OUT_OFF + 131072ull)   // 20.14 MB

// ---------------------------------------------------------------------------
// Shared per-point voxel math — bit-identical to the R3..R8 passing kernels.
// ---------------------------------------------------------------------------
__device__ __forceinline__ void voxel_hash_d(float px, float py, float pz,
                                             int& hw, unsigned& dbits)
{
#pragma clang fp contract(off)
    float fx = floorf(px * RINV);
    float fy = floorf(py * RINV);
    float fz = floorf(pz * RINV);

    long long gx = (long long)fx;
    long long gy = (long long)fy;
    long long gz = (long long)fz;
    long long s = gx * 73856093LL + gy * 19349669LL + gz * 83492791LL;
    long long h = s % (long long)BUFSZ;           // trunc, sign of dividend
    hw = (int)(h < 0 ? h + BUFSZ : h);

    float cx = (fx + 0.5f) * RESF;
    float cy = (fy + 0.5f) * RESF;
    float cz = (fz + 0.5f) * RESF;
    float dx = px - cx;
    float dy = py - cy;
    float dz = pz - cz;
    float d = dx * dx + dy * dy + dz * dz;        // no fp contraction
    dbits = __float_as_uint(d);
}

// ===========================================================================
// K1: multisplit binning (R8-proven) + fused {neural,ts}->pnt pack.
// The pack is pure streaming and rides under the fire-and-forget LDS/global
// atomics of the scatter phase (R6 lesson: disjoint buffers, atomics first).
// ===========================================================================
__global__ __launch_bounds__(256) void bin_pack(
    const float* __restrict__ points,
    unsigned long long* __restrict__ bins_e,
    unsigned int* __restrict__ ctl,
    unsigned long long* __restrict__ ovf,
    const float* __restrict__ neural,
    const int* __restrict__ ts_upd,
    float4* __restrict__ pnt,
    int N, int M)
{
    __shared__ unsigned int cnt[NBINS];
    int t = threadIdx.x;
    for (int b = t; b < NBINS; b += 256) cnt[b] = 0;
    __syncthreads();

    int base = blockIdx.x * (256 * 16);
    unsigned hwv[16];
    unsigned dbv[16];

#pragma unroll
    for (int k = 0; k < 16; ++k) {
        int i = base + t + k * 256;
        hwv[k] = 0xFFFFFFFFu;                      // sentinel: invalid
        dbv[k] = 0;
        if (i < N) {
            int hw; unsigned db;
            voxel_hash_d(points[3 * i], points[3 * i + 1], points[3 * i + 2],
                         hw, db);
            hwv[k] = (unsigned)hw;
            dbv[k] = db;
            if (db <= 0x3FFFFFFFu)
                atomicAdd(&cnt[hw >> BIN_SHIFT], 1u);
        }
    }
    __syncthreads();

    // reserve global ranges; cnt[b] becomes the block's running global cursor
    for (int b = t; b < NBINS; b += 256) {
        unsigned c = cnt[b];
        cnt[b] = c ? atomicAdd(&ctl[b], c) : 0u;
    }
    __syncthreads();

#pragma unroll
    for (int k = 0; k < 16; ++k) {
        if (hwv[k] == 0xFFFFFFFFu) continue;
        unsigned hw = hwv[k], db = dbv[k];
        if (db <= 0x3FFFFFFFu) {
            unsigned bin = hw >> BIN_SHIFT;
            unsigned idx = atomicAdd(&cnt[bin], 1u);
            if (idx < BIN_CAP) {
                bins_e[(size_t)bin * BIN_CAP + idx] =
                    ((unsigned long long)db << BIN_SHIFT)
                    | (hw & (BKT_PER_BIN - 1));
                continue;
            }
        }
        unsigned o = atomicAdd(&ctl[NBINS], 1u);
        if (o < OVF_CAP)
            ovf[o] = ((unsigned long long)db << 32) | hw;
    }

    // fused pack: streams while the scatter atomics retire (disjoint buffers)
    int T = gridDim.x * 256;
    for (int j = blockIdx.x * 256 + t; j < M; j += T)
        pnt[j] = make_float4(neural[3 * j], neural[3 * j + 1],
                             neural[3 * j + 2], __int_as_float(ts_upd[j]));
}

// ===========================================================================
// K2: per-bin LDS segment-min + sequential uint4 writeback fused with the
// bufidx pack. 32 KB LDS -> ~5 blocks/CU; 1221 blocks = one full wave.
// ===========================================================================
__global__ __launch_bounds__(256) void min_bins(
    const unsigned long long* __restrict__ bins_e,
    const unsigned int* __restrict__ ctl,
    const int2* __restrict__ bufidx2,
    uint4* __restrict__ p8q)           // p8 viewed as uint4[5M] (2 buckets each)
{
    __shared__ unsigned int tbl[BKT_PER_BIN];      // 32 KB
    int t = threadIdx.x;
    int b = blockIdx.x;

    uint4* t4 = (uint4*)tbl;
    for (int l = t; l < BKT_PER_BIN / 4; l += 256)
        t4[l] = make_uint4(0xFFFFFFFFu, 0xFFFFFFFFu, 0xFFFFFFFFu, 0xFFFFFFFFu);
    __syncthreads();

    unsigned c = ctl[b];
    if (c > BIN_CAP) c = BIN_CAP;                  // excess went to ovf
    const unsigned long long* e = bins_e + (size_t)b * BIN_CAP;
    for (unsigned j = t; j < c; j += 256) {
        unsigned long long v = e[j];
        atomicMin(&tbl[(unsigned)(v & (BKT_PER_BIN - 1))],
                  (unsigned)(v >> BIN_SHIFT));
    }
    __syncthreads();

    // writeback: pair of buckets per uint4 store, bufidx read as int2
    long long pbase = (long long)b * (BKT_PER_BIN / 2);   // pair index base
    for (int l = t; l < BKT_PER_BIN / 2; l += 256) {
        long long pp = pbase + l;                  // global pair index
        long long g = 2 * pp;                      // global bucket index
        if (g + 1 < (long long)BUFSZ) {
            int2 bi = bufidx2[pp];
            p8q[pp] = make_uint4(tbl[2 * l], (unsigned)bi.x,
                                 tbl[2 * l + 1], (unsigned)bi.y);
        }
    }
}

// ===========================================================================
// K3: drain overflow entries (statistically empty) with exact global atomics.
// ===========================================================================
__global__ __launch_bounds__(256) void fix_ovf(
    const unsigned int* __restrict__ ctl,
    const unsigned long long* __restrict__ ovf,
    unsigned int* __restrict__ p8w)
{
    unsigned c = ctl[NBINS];
    if (c > OVF_CAP) c = OVF_CAP;
    for (unsigned e = threadIdx.x; e < c; e += 256) {
        unsigned long long v = ovf[e];
        atomicMin(p8w + 2ull * (unsigned)(v & 0xFFFFFFFFu), (unsigned)(v >> 32));
    }
}

// ===========================================================================
// K4: output pass, 4 independent points per thread — at the 2-random-lines/
// point permutation floor (49 G line-touches/s measured). Unchanged from R8.
// ===========================================================================
__global__ __launch_bounds__(256) void pass_out_A4(
    const float* __restrict__ points,
    const uint2* __restrict__ p8,
    const float4* __restrict__ pnt,
    const float* __restrict__ travel,
    const int* __restrict__ cur_ts_p,
    float* __restrict__ out,
    int N, int M, int S)               // S = ceil(N/4)
{
#pragma clang fp contract(off)
    int tid = blockIdx.x * 256 + threadIdx.x;
    if (tid >= S) return;

    float tcur = travel[cur_ts_p[0]];

    int      iv[4];
    bool     val[4];
    float    pxv[4], pyv[4], pzv[4];
    int      hwv[4];
    unsigned dbv[4];

#pragma unroll
    for (int k = 0; k < 4; ++k) {
        int i = tid + k * S;
        val[k] = (i < N);
        iv[k]  = val[k] ? i : 0;
        pxv[k] = points[3 * iv[k] + 0];
        pyv[k] = points[3 * iv[k] + 1];
        pzv[k] = points[3 * iv[k] + 2];
        voxel_hash_d(pxv[k], pyv[k], pzv[k], hwv[k], dbv[k]);
    }

    uint2 ev[4];
#pragma unroll
    for (int k = 0; k < 4; ++k) ev[k] = p8[hwv[k]];

    int hidxv[4], idxwv[4];
    float4 ntv[4];
#pragma unroll
    for (int k = 0; k < 4; ++k) {
        hidxv[k] = (int)ev[k].y;
        idxwv[k] = (hidxv[k] < 0) ? (hidxv[k] + M) : hidxv[k];
    }
#pragma unroll
    for (int k = 0; k < 4; ++k) ntv[k] = pnt[idxwv[k]];

#pragma unroll
    for (int k = 0; k < 4; ++k) {
        if (!val[k]) continue;

        bool keep = dbv[k] <= ev[k].x;

        float vx = ntv[k].x - pxv[k];
        float vy = ntv[k].y - pyv[k];
        float vz = ntv[k].z - pzv[k];
        float dist2 = vx * vx + vy * vy + vz * vz;

        int ts = __float_as_int(ntv[k].w);
        float dtv = tcur - travel[ts];

        const float THR = (float)(3.0 * 0.3 * 0.3);
        bool upd = keep && ((hidxv[k] == -1) || (dist2 > THR) || (dtv > 120.0f));

        out[iv[k]]         = dist2;
        out[N + iv[k]]     = dtv;
        out[2 * N + iv[k]] = upd ? 1.0f : 0.0f;
    }
}

// ===========================================================================
// Tier C fallback (proven in R3): used only if ws/out don't fit the fast path.
// ===========================================================================
__global__ __launch_bounds__(256) void pass_min_C(
    const float* __restrict__ points, unsigned int* __restrict__ seg, int N)
{
    int i = blockIdx.x * 256 + threadIdx.x;
    if (i >= N) return;
    int hw; unsigned dbits;
    voxel_hash_d(points[3 * i], points[3 * i + 1], points[3 * i + 2], hw, dbits);
    atomicMin(seg + hw, dbits);
}

__global__ __launch_bounds__(256) void pass_out_C(
    const float* __restrict__ points, const float* __restrict__ neural,
    const int* __restrict__ bufidx, const float* __restrict__ travel,
    const int* __restrict__ ts_upd, const int* __restrict__ cur_ts_p,
    const unsigned int* __restrict__ seg, float* __restrict__ out, int N, int M)
{
#pragma clang fp contract(off)
    int i = blockIdx.x * 256 + threadIdx.x;
    if (i >= N) return;
    float px = points[3 * i], py = points[3 * i + 1], pz = points[3 * i + 2];
    int hw; unsigned dbits;
    voxel_hash_d(px, py, pz, hw, dbits);
    bool keep = dbits <= seg[hw];
    int hidx = bufidx[hw];
    int idxw = (hidx < 0) ? (hidx + M) : hidx;
    float vx = neural[3 * idxw] - px;
    float vy = neural[3 * idxw + 1] - py;
    float vz = neural[3 * idxw + 2] - pz;
    float dist2 = vx * vx + vy * vy + vz * vz;
    int ts = ts_upd[idxw];
    float dtv = travel[cur_ts_p[0]] - travel[ts];
    const float THR = (float)(3.0 * 0.3 * 0.3);
    bool upd = keep && ((hidx == -1) || (dist2 > THR) || (dtv > 120.0f));
    out[i] = dist2;
    out[N + i] = dtv;
    out[2 * N + i] = upd ? 1.0f : 0.0f;
}

extern "C" void kernel_launch(void* const* d_in, const int* in_sizes, int n_in,
                              void* d_out, int out_size, void* d_ws, size_t ws_size,
                              hipStream_t stream)
{
    const float* points  = (const float*)d_in[0];
    const float* neural  = (const float*)d_in[1];
    const int*   bufidx  = (const int*)d_in[2];
    const float* travel  = (const float*)d_in[3];
    const int*   ts_upd  = (const int*)d_in[4];
    const int*   cur_ts  = (const int*)d_in[5];

    int N = in_sizes[0] / 3;
    int M = in_sizes[1] / 3;

    const size_t needWs = (size_t)BUFSZ * 8 + (size_t)M * 16;   // 112 MB
    if (ws_size >= needWs && (size_t)out_size * 4 >= OUT_NEED) {
        char* ws = (char*)d_ws;
        char* ob = (char*)d_out;
        uint2*              p8   = (uint2*)ws;                    // 80 MB
        float4*             pnt  = (float4*)(ws + PNT_WS_OFF);    // 32 MB
        unsigned long long* e64  = (unsigned long long*)(ob + E64_OUT_OFF);
        unsigned int*       ctl  = (unsigned int*)(ob + CTL_OUT_OFF);
        unsigned long long* ovf  = (unsigned long long*)(ob + OVF_OUT_OFF);

        hipMemsetAsync(ctl, 0, 8192, stream);

        int bblocks = (N + 4095) / 4096;
        bin_pack<<<bblocks, 256, 0, stream>>>(points, e64, ctl, ovf,
                                              neural, ts_upd, pnt, N, M);
        min_bins<<<NBINS, 256, 0, stream>>>(e64, ctl, (const int2*)bufidx,
                                            (uint4*)p8);
        fix_ovf<<<1, 256, 0, stream>>>(ctl, ovf, (unsigned int*)p8);

        int S = (N + 3) / 4;
        int oblocks = (S + 255) / 256;
        pass_out_A4<<<oblocks, 256, 0, stream>>>(points, p8, pnt, travel, cur_ts,
                                                 (float*)d_out, N, M, S);
    } else {
        unsigned int* seg = (unsigned int*)d_ws;                  // 40 MB
        hipMemsetAsync(seg, 0xFF, (size_t)BUFSZ * sizeof(unsigned int), stream);
        int pblocks = (N + 255) / 256;
        pass_min_C<<<pblocks, 256, 0, stream>>>(points, seg, N);
        pass_out_C<<<pblocks, 256, 0, stream>>>(points, neural, bufidx, travel,
                                                ts_upd, cur_ts, seg,
                                                (float*)d_out, N, M);
    }
}

// Round 11
// 146.979 us; speedup vs baseline: 1.7412x; 1.0987x over previous
//
#include <hip/hip_runtime.h>

#define BUFSZ 10000000
#define RESF 0.3f
// XLA canonicalizes x / const -> x * (1/const); 1.0f/0.3f folds to 0x40555555.
#define RINV (1.0f / 0.3f)

// ---- binning geometry -----------------------------------------------------
#define BIN_SHIFT   13
#define BKT_PER_BIN 8192                   // buckets per bin (32 KB LDS table)
#define NBINS       1221                   // ceil(10M / 8192)
#define BIN_CAP     2048                   // slots/bin (mean 1638 @ N=2M)
#define NSLOTS      (NBINS * BIN_CAP)      // 2,500,608
#define OVF_CAP     16384

// ---- scratch layout -------------------------------------------------------
// d_out as scratch (24 MB, fully rewritten by pass_out_S4):
//   [0, 20,004,864)        e64  u64[NSLOTS]  {db(30)<<13 | lbkt(13)}
//   [20,004,864, +8KB)     ctl  u32[NBINS] counts + [NBINS] = ovf count
//   [20,013,056, +128KB)   ovfA u64[OVF_CAP] {db<<24 | hw}
// ws (proven >= 112 MB):
//   [0, 32M)               pnt     float4[2M] {x,y,z,ts}
//   [32M, 40M)             slot32  u32[N]  (point -> slot, 0x8000_0000|o = ovf)
//   [40M, 50,002,432)      res32   u32[NSLOTS] {keep<<31 | (hidx+1)}
//   [50,002,432, +64KB)    res_ovf u32[OVF_CAP]
#define E64_OUT_OFF 0ull
#define CTL_OUT_OFF 20004864ull
#define OVF_OUT_OFF 20013056ull
#define OUT_NEED    (OVF_OUT_OFF + 131072ull)

#define PNT_WS_OFF   0ull
#define SLOT_WS_OFF  32000000ull
#define RES_WS_OFF   40000000ull
#define ROVF_WS_OFF  50002432ull
#define WS_NEED      (ROVF_WS_OFF + 65536ull)

// ---------------------------------------------------------------------------
// Shared per-point voxel math — bit-identical to the R3..R10 passing kernels.
// ---------------------------------------------------------------------------
__device__ __forceinline__ void voxel_hash_d(float px, float py, float pz,
                                             int& hw, unsigned& dbits)
{
#pragma clang fp contract(off)
    float fx = floorf(px * RINV);
    float fy = floorf(py * RINV);
    float fz = floorf(pz * RINV);

    long long gx = (long long)fx;
    long long gy = (long long)fy;
    long long gz = (long long)fz;
    long long s = gx * 73856093LL + gy * 19349669LL + gz * 83492791LL;
    long long h = s % (long long)BUFSZ;           // trunc, sign of dividend
    hw = (int)(h < 0 ? h + BUFSZ : h);

    float cx = (fx + 0.5f) * RESF;
    float cy = (fy + 0.5f) * RESF;
    float cz = (fz + 0.5f) * RESF;
    float dx = px - cx;
    float dy = py - cy;
    float dz = pz - cz;
    float d = dx * dx + dy * dy + dz * dz;        // no fp contraction
    dbits = __float_as_uint(d);
}

// ===========================================================================
// K1: multisplit binning + dense point->slot map (no pidx in entries).
// ===========================================================================
__global__ __launch_bounds__(256) void bin_slot(
    const float* __restrict__ points,
    unsigned long long* __restrict__ e64,
    unsigned int* __restrict__ ctl,
    unsigned long long* __restrict__ ovfA,
    unsigned int* __restrict__ slot32,
    int N)
{
    __shared__ unsigned int cnt[NBINS];
    int t = threadIdx.x;
    for (int b = t; b < NBINS; b += 256) cnt[b] = 0;
    __syncthreads();

    int base = blockIdx.x * (256 * 16);
    unsigned hwv[16];
    unsigned dbv[16];

#pragma unroll
    for (int k = 0; k < 16; ++k) {
        int i = base + t + k * 256;
        hwv[k] = 0xFFFFFFFFu;                      // sentinel: i >= N
        dbv[k] = 0;
        if (i < N) {
            int hw; unsigned db;
            voxel_hash_d(points[3 * i], points[3 * i + 1], points[3 * i + 2],
                         hw, db);
            hwv[k] = (unsigned)hw;
            dbv[k] = db;
            if (db <= 0x3FFFFFFFu)
                atomicAdd(&cnt[hw >> BIN_SHIFT], 1u);
        }
    }
    __syncthreads();

    // reserve global ranges; cnt[b] becomes the block's running global cursor
    for (int b = t; b < NBINS; b += 256) {
        unsigned c = cnt[b];
        cnt[b] = c ? atomicAdd(&ctl[b], c) : 0u;
    }
    __syncthreads();

#pragma unroll
    for (int k = 0; k < 16; ++k) {
        if (hwv[k] == 0xFFFFFFFFu) continue;
        int i = base + t + k * 256;
        unsigned hw = hwv[k], db = dbv[k];
        if (db <= 0x3FFFFFFFu) {
            unsigned bin = hw >> BIN_SHIFT;
            unsigned idx = atomicAdd(&cnt[bin], 1u);
            if (idx < BIN_CAP) {
                unsigned slot = bin * BIN_CAP + idx;
                e64[slot] = ((unsigned long long)db << BIN_SHIFT)
                          | (hw & (BKT_PER_BIN - 1));
                slot32[i] = slot;
                continue;
            }
        }
        unsigned o = atomicAdd(&ctl[NBINS], 1u);
        unsigned oc = (o < OVF_CAP) ? o : (OVF_CAP - 1);
        if (o < OVF_CAP)
            ovfA[o] = ((unsigned long long)db << 24) | hw;   // hw < 2^24
        slot32[i] = 0x80000000u | oc;
    }
}

// ===========================================================================
// K2: stream-pack {neural, ts} -> pnt (pure streaming, split per R10 lesson).
// ===========================================================================
__global__ __launch_bounds__(256) void pack_pnt(
    const float* __restrict__ neural,
    const int* __restrict__ ts_upd,
    float4* __restrict__ pnt, int M)
{
    int T = gridDim.x * 256;
    for (int j = blockIdx.x * 256 + threadIdx.x; j < M; j += T)
        pnt[j] = make_float4(neural[3 * j], neural[3 * j + 1],
                             neural[3 * j + 2], __int_as_float(ts_upd[j]));
}

// ===========================================================================
// K3: per-bin LDS segment-min, then per-ENTRY result record (dense writes):
// res32[slot] = keep(1) << 31 | (hidx+1)(22 bits). bufidx reads confined to
// the bin's 32 KB window (L2-hot). ovf entries folded in for exact mins.
// ===========================================================================
__global__ __launch_bounds__(256) void min_res(
    const unsigned long long* __restrict__ e64,
    const unsigned int* __restrict__ ctl,
    const unsigned long long* __restrict__ ovfA,
    const int* __restrict__ bufidx,
    unsigned int* __restrict__ res32)
{
    __shared__ unsigned int tbl[BKT_PER_BIN];      // 32 KB
    int t = threadIdx.x;
    int b = blockIdx.x;

    uint4* t4 = (uint4*)tbl;
    for (int l = t; l < BKT_PER_BIN / 4; l += 256)
        t4[l] = make_uint4(0xFFFFFFFFu, 0xFFFFFFFFu, 0xFFFFFFFFu, 0xFFFFFFFFu);
    __syncthreads();

    unsigned c = ctl[b];
    if (c > BIN_CAP) c = BIN_CAP;                  // excess went to ovf
    size_t ebase = (size_t)b * BIN_CAP;
    for (unsigned j = t; j < c; j += 256) {
        unsigned long long v = e64[ebase + j];
        atomicMin(&tbl[(unsigned)(v & (BKT_PER_BIN - 1))],
                  (unsigned)(v >> BIN_SHIFT));
    }

    unsigned ovfn = ctl[NBINS];
    if (ovfn > OVF_CAP) ovfn = OVF_CAP;
    unsigned gbase = (unsigned)b << BIN_SHIFT;
    for (unsigned o = t; o < ovfn; o += 256) {     // statistically empty
        unsigned long long va = ovfA[o];
        unsigned hw = (unsigned)(va & 0xFFFFFFu);
        if ((hw >> BIN_SHIFT) == (unsigned)b)
            atomicMin(&tbl[hw & (BKT_PER_BIN - 1)], (unsigned)(va >> 24));
    }
    __syncthreads();

    for (unsigned j = t; j < c; j += 256) {
        unsigned long long v = e64[ebase + j];
        unsigned lb = (unsigned)(v & (BKT_PER_BIN - 1));
        unsigned db = (unsigned)(v >> BIN_SHIFT);

        bool keep = db <= tbl[lb];
        int hidx = bufidx[gbase + lb];             // 32 KB window -> L2-hot
        res32[ebase + j] = (keep ? 0x80000000u : 0u) | (unsigned)(hidx + 1);
    }
}

// ===========================================================================
// K4: exact results for overflow entries (statistically none). Scans the
// bin's entries + other ovf entries for the true bucket min.
// ===========================================================================
__global__ __launch_bounds__(256) void fix_ovf2(
    const unsigned long long* __restrict__ e64,
    const unsigned int* __restrict__ ctl,
    const unsigned long long* __restrict__ ovfA,
    const int* __restrict__ bufidx,
    unsigned int* __restrict__ res_ovf)
{
    unsigned ovfn = ctl[NBINS];
    if (ovfn > OVF_CAP) ovfn = OVF_CAP;
    for (unsigned o = threadIdx.x; o < ovfn; o += 256) {
        unsigned long long va = ovfA[o];
        unsigned hw = (unsigned)(va & 0xFFFFFFu);
        unsigned db = (unsigned)(va >> 24);
        unsigned bin = hw >> BIN_SHIFT;
        unsigned lb  = hw & (BKT_PER_BIN - 1);

        unsigned mn = 0xFFFFFFFFu;
        unsigned c = ctl[bin];
        if (c > BIN_CAP) c = BIN_CAP;
        const unsigned long long* e = e64 + (size_t)bin * BIN_CAP;
        for (unsigned j = 0; j < c; ++j) {
            unsigned long long v = e[j];
            if ((unsigned)(v & (BKT_PER_BIN - 1)) == lb) {
                unsigned d2 = (unsigned)(v >> BIN_SHIFT);
                if (d2 < mn) mn = d2;
            }
        }
        for (unsigned o2 = 0; o2 < ovfn; ++o2) {
            unsigned long long v2 = ovfA[o2];
            if ((unsigned)(v2 & 0xFFFFFFu) == hw) {
                unsigned d2 = (unsigned)(v2 >> 24);
                if (d2 < mn) mn = d2;
            }
        }
        bool keep = db <= mn;
        int hidx = bufidx[hw];
        res_ovf[o] = (keep ? 0x80000000u : 0u) | (unsigned)(hidx + 1);
    }
}

// ===========================================================================
// K5: output pass — slot32 (dense) -> res32 (random 4B) -> pnt (random 16B).
// 4 independent chains/thread; throughput-bound at the line-fill ceiling.
// ===========================================================================
__global__ __launch_bounds__(256) void pass_out_S4(
    const float* __restrict__ points,
    const unsigned int* __restrict__ slot32,
    const unsigned int* __restrict__ res32,
    const unsigned int* __restrict__ res_ovf,
    const float4* __restrict__ pnt,
    const float* __restrict__ travel,
    const int* __restrict__ cur_ts_p,
    float* __restrict__ out,
    int N, int M, int S)               // S = ceil(N/4)
{
#pragma clang fp contract(off)
    int tid = blockIdx.x * 256 + threadIdx.x;
    if (tid >= S) return;

    float tcur = travel[cur_ts_p[0]];

    int      iv[4];
    bool     val[4];
    float    pxv[4], pyv[4], pzv[4];
    unsigned sv[4];

#pragma unroll
    for (int k = 0; k < 4; ++k) {
        int i = tid + k * S;
        val[k] = (i < N);
        iv[k]  = val[k] ? i : 0;
        pxv[k] = points[3 * iv[k] + 0];
        pyv[k] = points[3 * iv[k] + 1];
        pzv[k] = points[3 * iv[k] + 2];
        sv[k]  = slot32[iv[k]];
    }

    unsigned rv[4];
#pragma unroll
    for (int k = 0; k < 4; ++k) {
        const unsigned* rp = (sv[k] & 0x80000000u)
                           ? (res_ovf + (sv[k] & 0x7FFFFFFFu))
                           : (res32 + sv[k]);
        rv[k] = *rp;                                // 1 random 4B gather
    }

    int hidxv[4], idxwv[4];
    float4 ntv[4];
#pragma unroll
    for (int k = 0; k < 4; ++k) {
        hidxv[k] = (int)(rv[k] & 0x7FFFFFFFu) - 1;  // -1 == empty
        idxwv[k] = (hidxv[k] < 0) ? (hidxv[k] + M) : hidxv[k];
    }
#pragma unroll
    for (int k = 0; k < 4; ++k) ntv[k] = pnt[idxwv[k]];  // 1 random 16B gather

#pragma unroll
    for (int k = 0; k < 4; ++k) {
        if (!val[k]) continue;

        bool keep = (rv[k] >> 31) != 0u;

        float vx = ntv[k].x - pxv[k];
        float vy = ntv[k].y - pyv[k];
        float vz = ntv[k].z - pzv[k];
        float dist2 = vx * vx + vy * vy + vz * vz;  // no contraction

        int ts = __float_as_int(ntv[k].w);
        float dtv = tcur - travel[ts];

        const float THR = (float)(3.0 * 0.3 * 0.3);
        bool upd = keep && ((hidxv[k] == -1) || (dist2 > THR) || (dtv > 120.0f));

        out[iv[k]]         = dist2;
        out[N + iv[k]]     = dtv;
        out[2 * N + iv[k]] = upd ? 1.0f : 0.0f;
    }
}

// ===========================================================================
// Tier C fallback (proven in R3): used only if ws/out don't fit the fast path.
// ===========================================================================
__global__ __launch_bounds__(256) void pass_min_C(
    const float* __restrict__ points, unsigned int* __restrict__ seg, int N)
{
    int i = blockIdx.x * 256 + threadIdx.x;
    if (i >= N) return;
    int hw; unsigned dbits;
    voxel_hash_d(points[3 * i], points[3 * i + 1], points[3 * i + 2], hw, dbits);
    atomicMin(seg + hw, dbits);
}

__global__ __launch_bounds__(256) void pass_out_C(
    const float* __restrict__ points, const float* __restrict__ neural,
    const int* __restrict__ bufidx, const float* __restrict__ travel,
    const int* __restrict__ ts_upd, const int* __restrict__ cur_ts_p,
    const unsigned int* __restrict__ seg, float* __restrict__ out, int N, int M)
{
#pragma clang fp contract(off)
    int i = blockIdx.x * 256 + threadIdx.x;
    if (i >= N) return;
    float px = points[3 * i], py = points[3 * i + 1], pz = points[3 * i + 2];
    int hw; unsigned dbits;
    voxel_hash_d(px, py, pz, hw, dbits);
    bool keep = dbits <= seg[hw];
    int hidx = bufidx[hw];
    int idxw = (hidx < 0) ? (hidx + M) : hidx;
    float vx = neural[3 * idxw] - px;
    float vy = neural[3 * idxw + 1] - py;
    float vz = neural[3 * idxw + 2] - pz;
    float dist2 = vx * vx + vy * vy + vz * vz;
    int ts = ts_upd[idxw];
    float dtv = travel[cur_ts_p[0]] - travel[ts];
    const float THR = (float)(3.0 * 0.3 * 0.3);
    bool upd = keep && ((hidx == -1) || (dist2 > THR) || (dtv > 120.0f));
    out[i] = dist2;
    out[N + i] = dtv;
    out[2 * N + i] = upd ? 1.0f : 0.0f;
}

extern "C" void kernel_launch(void* const* d_in, const int* in_sizes, int n_in,
                              void* d_out, int out_size, void* d_ws, size_t ws_size,
                              hipStream_t stream)
{
    const float* points  = (const float*)d_in[0];
    const float* neural  = (const float*)d_in[1];
    const int*   bufidx  = (const int*)d_in[2];
    const float* travel  = (const float*)d_in[3];
    const int*   ts_upd  = (const int*)d_in[4];
    const int*   cur_ts  = (const int*)d_in[5];

    int N = in_sizes[0] / 3;
    int M = in_sizes[1] / 3;

    if (ws_size >= WS_NEED && (size_t)out_size * 4 >= OUT_NEED
        && N <= 2100000 && (size_t)N * 4 <= (RES_WS_OFF - SLOT_WS_OFF)) {
        char* ws = (char*)d_ws;
        char* ob = (char*)d_out;
        float4*             pnt     = (float4*)(ws + PNT_WS_OFF);
        unsigned int*       slot32  = (unsigned int*)(ws + SLOT_WS_OFF);
        unsigned int*       res32   = (unsigned int*)(ws + RES_WS_OFF);
        unsigned int*       res_ovf = (unsigned int*)(ws + ROVF_WS_OFF);
        unsigned long long* e64     = (unsigned long long*)(ob + E64_OUT_OFF);
        unsigned int*       ctl     = (unsigned int*)(ob + CTL_OUT_OFF);
        unsigned long long* ovfA    = (unsigned long long*)(ob + OVF_OUT_OFF);

        hipMemsetAsync(ctl, 0, 8192, stream);

        int bblocks = (N + 4095) / 4096;
        bin_slot<<<bblocks, 256, 0, stream>>>(points, e64, ctl, ovfA, slot32, N);
        pack_pnt<<<2048, 256, 0, stream>>>(neural, ts_upd, pnt, M);
        min_res<<<NBINS, 256, 0, stream>>>(e64, ctl, ovfA, bufidx, res32);
        fix_ovf2<<<1, 256, 0, stream>>>(e64, ctl, ovfA, bufidx, res_ovf);

        int S = (N + 3) / 4;
        int oblocks = (S + 255) / 256;
        pass_out_S4<<<oblocks, 256, 0, stream>>>(points, slot32, res32, res_ovf,
                                                 pnt, travel, cur_ts,
                                                 (float*)d_out, N, M, S);
    } else {
        unsigned int* seg = (unsigned int*)d_ws;                  // 40 MB
        hipMemsetAsync(seg, 0xFF, (size_t)BUFSZ * sizeof(unsigned int), stream);
        int pblocks = (N + 255) / 256;
        pass_min_C<<<pblocks, 256, 0, stream>>>(points, seg, N);
        pass_out_C<<<pblocks, 256, 0, stream>>>(points, neural, bufidx, travel,
                                                ts_upd, cur_ts, seg,
                                                (float*)d_out, N, M);
    }
}

// Round 12
// 140.981 us; speedup vs baseline: 1.8153x; 1.0425x over previous
//
#include <hip/hip_runtime.h>

#define BUFSZ 10000000
#define RESF 0.3f
// XLA canonicalizes x / const -> x * (1/const); 1.0f/0.3f folds to 0x40555555.
#define RINV (1.0f / 0.3f)

// ---- binning geometry -----------------------------------------------------
#define BIN_SHIFT   13
#define BKT_PER_BIN 8192                   // buckets per bin (32 KB LDS table)
#define NBINS       1221                   // ceil(10M / 8192)
#define BIN_CAP     2048                   // slots/bin (mean 1638 @ N=2M)
#define NSLOTS      (NBINS * BIN_CAP)      // 2,500,608
#define OVF_CAP     16384
#define PACKB       2048                   // streaming pack blocks in merged K2

// ---- scratch layout -------------------------------------------------------
// d_out as scratch (24 MB, fully rewritten by pass_out_S4):
//   [0, 20,004,864)        e64  u64[NSLOTS]  {db(30)<<13 | lbkt(13)}
//   [20,004,864, +8KB)     ctl  u32[NBINS] counts + [NBINS] = ovf count
//   [20,013,056, +128KB)   ovfA u64[OVF_CAP] {db<<24 | hw}
// ws (proven >= 112 MB):
//   [0, 32M)               pnt     float4[2M] {x,y,z,ts}
//   [32M, 40M)             slot32  u32[N]  (point -> slot, 0x8000_0000|o = ovf)
//   [40M, 50,002,432)      res32   u32[NSLOTS] {keep<<31 | (hidx+1)}
//   [50,002,432, +64KB)    res_ovf u32[OVF_CAP]
#define E64_OUT_OFF 0ull
#define CTL_OUT_OFF 20004864ull
#define OVF_OUT_OFF 20013056ull
#define OUT_NEED    (OVF_OUT_OFF + 131072ull)

#define PNT_WS_OFF   0ull
#define SLOT_WS_OFF  32000000ull
#define RES_WS_OFF   40000000ull
#define ROVF_WS_OFF  50002432ull
#define WS_NEED      (ROVF_WS_OFF + 65536ull)

// ---------------------------------------------------------------------------
// Shared per-point voxel math — bit-identical to the R3..R11 passing kernels.
// ---------------------------------------------------------------------------
__device__ __forceinline__ void voxel_hash_d(float px, float py, float pz,
                                             int& hw, unsigned& dbits)
{
#pragma clang fp contract(off)
    float fx = floorf(px * RINV);
    float fy = floorf(py * RINV);
    float fz = floorf(pz * RINV);

    long long gx = (long long)fx;
    long long gy = (long long)fy;
    long long gz = (long long)fz;
    long long s = gx * 73856093LL + gy * 19349669LL + gz * 83492791LL;
    long long h = s % (long long)BUFSZ;           // trunc, sign of dividend
    hw = (int)(h < 0 ? h + BUFSZ : h);

    float cx = (fx + 0.5f) * RESF;
    float cy = (fy + 0.5f) * RESF;
    float cz = (fz + 0.5f) * RESF;
    float dx = px - cx;
    float dy = py - cy;
    float dz = pz - cz;
    float d = dx * dx + dy * dy + dz * dz;        // no fp contraction
    dbits = __float_as_uint(d);
}

// ===========================================================================
// K1: multisplit binning + dense point->slot map (unchanged from R11).
// ===========================================================================
__global__ __launch_bounds__(256) void bin_slot(
    const float* __restrict__ points,
    unsigned long long* __restrict__ e64,
    unsigned int* __restrict__ ctl,
    unsigned long long* __restrict__ ovfA,
    unsigned int* __restrict__ slot32,
    int N)
{
    __shared__ unsigned int cnt[NBINS];
    int t = threadIdx.x;
    for (int b = t; b < NBINS; b += 256) cnt[b] = 0;
    __syncthreads();

    int base = blockIdx.x * (256 * 16);
    unsigned hwv[16];
    unsigned dbv[16];

#pragma unroll
    for (int k = 0; k < 16; ++k) {
        int i = base + t + k * 256;
        hwv[k] = 0xFFFFFFFFu;                      // sentinel: i >= N
        dbv[k] = 0;
        if (i < N) {
            int hw; unsigned db;
            voxel_hash_d(points[3 * i], points[3 * i + 1], points[3 * i + 2],
                         hw, db);
            hwv[k] = (unsigned)hw;
            dbv[k] = db;
            if (db <= 0x3FFFFFFFu)
                atomicAdd(&cnt[hw >> BIN_SHIFT], 1u);
        }
    }
    __syncthreads();

    // reserve global ranges; cnt[b] becomes the block's running global cursor
    for (int b = t; b < NBINS; b += 256) {
        unsigned c = cnt[b];
        cnt[b] = c ? atomicAdd(&ctl[b], c) : 0u;
    }
    __syncthreads();

#pragma unroll
    for (int k = 0; k < 16; ++k) {
        if (hwv[k] == 0xFFFFFFFFu) continue;
        int i = base + t + k * 256;
        unsigned hw = hwv[k], db = dbv[k];
        if (db <= 0x3FFFFFFFu) {
            unsigned bin = hw >> BIN_SHIFT;
            unsigned idx = atomicAdd(&cnt[bin], 1u);
            if (idx < BIN_CAP) {
                unsigned slot = bin * BIN_CAP + idx;
                e64[slot] = ((unsigned long long)db << BIN_SHIFT)
                          | (hw & (BKT_PER_BIN - 1));
                slot32[i] = slot;
                continue;
            }
        }
        unsigned o = atomicAdd(&ctl[NBINS], 1u);
        unsigned oc = (o < OVF_CAP) ? o : (OVF_CAP - 1);
        if (o < OVF_CAP)
            ovfA[o] = ((unsigned long long)db << 24) | hw;   // hw < 2^24
        slot32[i] = 0x80000000u | oc;
    }
}

// ===========================================================================
// K2 (merged, heterogeneous grid):
//   blocks [0, NBINS)      : per-bin LDS segment-min -> res32 (dense writes)
//   block  NBINS           : exact ovf drain -> res_ovf (statistically empty)
//   blocks (NBINS, +PACKB] : stream-pack {neural,ts} -> pnt
// Streaming pack blocks co-resident with LDS-atomic min blocks => the 72 MB
// pack rides under the atomic phase (R6 lesson, done at block granularity).
// All three roles write disjoint buffers; inputs are K1 outputs. No races.
// ===========================================================================
__global__ __launch_bounds__(256) void min_pack_ovf(
    const unsigned long long* __restrict__ e64,
    const unsigned int* __restrict__ ctl,
    const unsigned long long* __restrict__ ovfA,
    const int* __restrict__ bufidx,
    unsigned int* __restrict__ res32,
    unsigned int* __restrict__ res_ovf,
    const float* __restrict__ neural,
    const int* __restrict__ ts_upd,
    float4* __restrict__ pnt,
    int M)
{
    __shared__ unsigned int tbl[BKT_PER_BIN];      // 32 KB (all roles reserve)
    int t = threadIdx.x;
    int b = blockIdx.x;

    if (b > NBINS) {
        // ---- role: streaming pack ----
        int pb = b - NBINS - 1;
        int T = PACKB * 256;
        for (int j = pb * 256 + t; j < M; j += T)
            pnt[j] = make_float4(neural[3 * j], neural[3 * j + 1],
                                 neural[3 * j + 2], __int_as_float(ts_upd[j]));
        return;
    }

    if (b == NBINS) {
        // ---- role: exact overflow drain (statistically empty) ----
        unsigned ovfn = ctl[NBINS];
        if (ovfn > OVF_CAP) ovfn = OVF_CAP;
        for (unsigned o = t; o < ovfn; o += 256) {
            unsigned long long va = ovfA[o];
            unsigned hw = (unsigned)(va & 0xFFFFFFu);
            unsigned db = (unsigned)(va >> 24);
            unsigned bin = hw >> BIN_SHIFT;
            unsigned lb  = hw & (BKT_PER_BIN - 1);

            unsigned mn = 0xFFFFFFFFu;
            unsigned c = ctl[bin];
            if (c > BIN_CAP) c = BIN_CAP;
            const unsigned long long* e = e64 + (size_t)bin * BIN_CAP;
            for (unsigned j = 0; j < c; ++j) {
                unsigned long long v = e[j];
                if ((unsigned)(v & (BKT_PER_BIN - 1)) == lb) {
                    unsigned d2 = (unsigned)(v >> BIN_SHIFT);
                    if (d2 < mn) mn = d2;
                }
            }
            for (unsigned o2 = 0; o2 < ovfn; ++o2) {
                unsigned long long v2 = ovfA[o2];
                if ((unsigned)(v2 & 0xFFFFFFu) == hw) {
                    unsigned d2 = (unsigned)(v2 >> 24);
                    if (d2 < mn) mn = d2;
                }
            }
            bool keep = db <= mn;
            int hidx = bufidx[hw];
            res_ovf[o] = (keep ? 0x80000000u : 0u) | (unsigned)(hidx + 1);
        }
        return;
    }

    // ---- role: per-bin LDS segment-min + dense result records ----
    uint4* t4 = (uint4*)tbl;
    for (int l = t; l < BKT_PER_BIN / 4; l += 256)
        t4[l] = make_uint4(0xFFFFFFFFu, 0xFFFFFFFFu, 0xFFFFFFFFu, 0xFFFFFFFFu);
    __syncthreads();

    unsigned c = ctl[b];
    if (c > BIN_CAP) c = BIN_CAP;                  // excess went to ovf
    size_t ebase = (size_t)b * BIN_CAP;
    for (unsigned j = t; j < c; j += 256) {
        unsigned long long v = e64[ebase + j];
        atomicMin(&tbl[(unsigned)(v & (BKT_PER_BIN - 1))],
                  (unsigned)(v >> BIN_SHIFT));
    }

    unsigned ovfn = ctl[NBINS];
    if (ovfn > OVF_CAP) ovfn = OVF_CAP;
    unsigned gbase = (unsigned)b << BIN_SHIFT;
    for (unsigned o = t; o < ovfn; o += 256) {     // statistically empty
        unsigned long long va = ovfA[o];
        unsigned hw = (unsigned)(va & 0xFFFFFFu);
        if ((hw >> BIN_SHIFT) == (unsigned)b)
            atomicMin(&tbl[hw & (BKT_PER_BIN - 1)], (unsigned)(va >> 24));
    }
    __syncthreads();

    for (unsigned j = t; j < c; j += 256) {
        unsigned long long v = e64[ebase + j];
        unsigned lb = (unsigned)(v & (BKT_PER_BIN - 1));
        unsigned db = (unsigned)(v >> BIN_SHIFT);

        bool keep = db <= tbl[lb];
        int hidx = bufidx[gbase + lb];             // 32 KB window -> L2-hot
        res32[ebase + j] = (keep ? 0x80000000u : 0u) | (unsigned)(hidx + 1);
    }
}

// ===========================================================================
// K3: output pass — slot32 (dense) -> res32 (random 4B) -> pnt (random 16B).
// Within ~8% of the random-line-fill roofline (composed model R11). Unchanged.
// ===========================================================================
__global__ __launch_bounds__(256) void pass_out_S4(
    const float* __restrict__ points,
    const unsigned int* __restrict__ slot32,
    const unsigned int* __restrict__ res32,
    const unsigned int* __restrict__ res_ovf,
    const float4* __restrict__ pnt,
    const float* __restrict__ travel,
    const int* __restrict__ cur_ts_p,
    float* __restrict__ out,
    int N, int M, int S)               // S = ceil(N/4)
{
#pragma clang fp contract(off)
    int tid = blockIdx.x * 256 + threadIdx.x;
    if (tid >= S) return;

    float tcur = travel[cur_ts_p[0]];

    int      iv[4];
    bool     val[4];
    float    pxv[4], pyv[4], pzv[4];
    unsigned sv[4];

#pragma unroll
    for (int k = 0; k < 4; ++k) {
        int i = tid + k * S;
        val[k] = (i < N);
        iv[k]  = val[k] ? i : 0;
        pxv[k] = points[3 * iv[k] + 0];
        pyv[k] = points[3 * iv[k] + 1];
        pzv[k] = points[3 * iv[k] + 2];
        sv[k]  = slot32[iv[k]];
    }

    unsigned rv[4];
#pragma unroll
    for (int k = 0; k < 4; ++k) {
        const unsigned* rp = (sv[k] & 0x80000000u)
                           ? (res_ovf + (sv[k] & 0x7FFFFFFFu))
                           : (res32 + sv[k]);
        rv[k] = *rp;                                // 1 random 4B gather
    }

    int hidxv[4], idxwv[4];
    float4 ntv[4];
#pragma unroll
    for (int k = 0; k < 4; ++k) {
        hidxv[k] = (int)(rv[k] & 0x7FFFFFFFu) - 1;  // -1 == empty
        idxwv[k] = (hidxv[k] < 0) ? (hidxv[k] + M) : hidxv[k];
    }
#pragma unroll
    for (int k = 0; k < 4; ++k) ntv[k] = pnt[idxwv[k]];  // 1 random 16B gather

#pragma unroll
    for (int k = 0; k < 4; ++k) {
        if (!val[k]) continue;

        bool keep = (rv[k] >> 31) != 0u;

        float vx = ntv[k].x - pxv[k];
        float vy = ntv[k].y - pyv[k];
        float vz = ntv[k].z - pzv[k];
        float dist2 = vx * vx + vy * vy + vz * vz;  // no contraction

        int ts = __float_as_int(ntv[k].w);
        float dtv = tcur - travel[ts];

        const float THR = (float)(3.0 * 0.3 * 0.3);
        bool upd = keep && ((hidxv[k] == -1) || (dist2 > THR) || (dtv > 120.0f));

        out[iv[k]]         = dist2;
        out[N + iv[k]]     = dtv;
        out[2 * N + iv[k]] = upd ? 1.0f : 0.0f;
    }
}

// ===========================================================================
// Tier C fallback (proven in R3): used only if ws/out don't fit the fast path.
// ===========================================================================
__global__ __launch_bounds__(256) void pass_min_C(
    const float* __restrict__ points, unsigned int* __restrict__ seg, int N)
{
    int i = blockIdx.x * 256 + threadIdx.x;
    if (i >= N) return;
    int hw; unsigned dbits;
    voxel_hash_d(points[3 * i], points[3 * i + 1], points[3 * i + 2], hw, dbits);
    atomicMin(seg + hw, dbits);
}

__global__ __launch_bounds__(256) void pass_out_C(
    const float* __restrict__ points, const float* __restrict__ neural,
    const int* __restrict__ bufidx, const float* __restrict__ travel,
    const int* __restrict__ ts_upd, const int* __restrict__ cur_ts_p,
    const unsigned int* __restrict__ seg, float* __restrict__ out, int N, int M)
{
#pragma clang fp contract(off)
    int i = blockIdx.x * 256 + threadIdx.x;
    if (i >= N) return;
    float px = points[3 * i], py = points[3 * i + 1], pz = points[3 * i + 2];
    int hw; unsigned dbits;
    voxel_hash_d(px, py, pz, hw, dbits);
    bool keep = dbits <= seg[hw];
    int hidx = bufidx[hw];
    int idxw = (hidx < 0) ? (hidx + M) : hidx;
    float vx = neural[3 * idxw] - px;
    float vy = neural[3 * idxw + 1] - py;
    float vz = neural[3 * idxw + 2] - pz;
    float dist2 = vx * vx + vy * vy + vz * vz;
    int ts = ts_upd[idxw];
    float dtv = travel[cur_ts_p[0]] - travel[ts];
    const float THR = (float)(3.0 * 0.3 * 0.3);
    bool upd = keep && ((hidx == -1) || (dist2 > THR) || (dtv > 120.0f));
    out[i] = dist2;
    out[N + i] = dtv;
    out[2 * N + i] = upd ? 1.0f : 0.0f;
}

extern "C" void kernel_launch(void* const* d_in, const int* in_sizes, int n_in,
                              void* d_out, int out_size, void* d_ws, size_t ws_size,
                              hipStream_t stream)
{
    const float* points  = (const float*)d_in[0];
    const float* neural  = (const float*)d_in[1];
    const int*   bufidx  = (const int*)d_in[2];
    const float* travel  = (const float*)d_in[3];
    const int*   ts_upd  = (const int*)d_in[4];
    const int*   cur_ts  = (const int*)d_in[5];

    int N = in_sizes[0] / 3;
    int M = in_sizes[1] / 3;

    if (ws_size >= WS_NEED && (size_t)out_size * 4 >= OUT_NEED
        && N <= 2100000 && (size_t)N * 4 <= (RES_WS_OFF - SLOT_WS_OFF)) {
        char* ws = (char*)d_ws;
        char* ob = (char*)d_out;
        float4*             pnt     = (float4*)(ws + PNT_WS_OFF);
        unsigned int*       slot32  = (unsigned int*)(ws + SLOT_WS_OFF);
        unsigned int*       res32   = (unsigned int*)(ws + RES_WS_OFF);
        unsigned int*       res_ovf = (unsigned int*)(ws + ROVF_WS_OFF);
        unsigned long long* e64     = (unsigned long long*)(ob + E64_OUT_OFF);
        unsigned int*       ctl     = (unsigned int*)(ob + CTL_OUT_OFF);
        unsigned long long* ovfA    = (unsigned long long*)(ob + OVF_OUT_OFF);

        hipMemsetAsync(ctl, 0, 8192, stream);

        int bblocks = (N + 4095) / 4096;
        bin_slot<<<bblocks, 256, 0, stream>>>(points, e64, ctl, ovfA, slot32, N);
        min_pack_ovf<<<NBINS + 1 + PACKB, 256, 0, stream>>>(
            e64, ctl, ovfA, bufidx, res32, res_ovf, neural, ts_upd, pnt, M);

        int S = (N + 3) / 4;
        int oblocks = (S + 255) / 256;
        pass_out_S4<<<oblocks, 256, 0, stream>>>(points, slot32, res32, res_ovf,
                                                 pnt, travel, cur_ts,
                                                 (float*)d_out, N, M, S);
    } else {
        unsigned int* seg = (unsigned int*)d_ws;                  // 40 MB
        hipMemsetAsync(seg, 0xFF, (size_t)BUFSZ * sizeof(unsigned int), stream);
        int pblocks = (N + 255) / 256;
        pass_min_C<<<pblocks, 256, 0, stream>>>(points, seg, N);
        pass_out_C<<<pblocks, 256, 0, stream>>>(points, neural, bufidx, travel,
                                                ts_upd, cur_ts, seg,
                                                (float*)d_out, N, M);
    }
}

// Round 13
// 140.432 us; speedup vs baseline: 1.8224x; 1.0039x over previous
//
#include <hip/hip_runtime.h>

#define BUFSZ 10000000
#define RESF 0.3f
// XLA canonicalizes x / const -> x * (1/const); 1.0f/0.3f folds to 0x40555555.
#define RINV (1.0f / 0.3f)

// ---- binning geometry -----------------------------------------------------
#define BIN_SHIFT   13
#define BKT_PER_BIN 8192                   // buckets per bin (32 KB LDS table)
#define NBINS       1221                   // ceil(10M / 8192)
#define BIN_CAP     2048                   // slots/bin (mean 1638 @ N=2M)
#define NSLOTS      (NBINS * BIN_CAP)      // 2,500,608
#define OVF_CAP     16384
#define PACKB       2048                   // streaming pack blocks in K1 grid

// ---- scratch layout -------------------------------------------------------
// d_out as scratch (24 MB, fully rewritten by pass_out_S4):
//   [0, 20,004,864)        e64  u64[NSLOTS]  {db(30)<<13 | lbkt(13)}
//   [20,004,864, +8KB)     ctl  u32[NBINS] counts + [NBINS] = ovf count
//   [20,013,056, +128KB)   ovfA u64[OVF_CAP] {db<<24 | hw}
// ws (proven >= 112 MB):
//   [0, 32M)               pnt     float4[2M] {x,y,z,ts}
//   [32M, 40M)             slot32  u32[N]  (point -> slot, 0x8000_0000|o = ovf)
//   [40M, 50,002,432)      res32   u32[NSLOTS] {keep<<31 | (hidx+1)}
//   [50,002,432, +64KB)    res_ovf u32[OVF_CAP]
#define E64_OUT_OFF 0ull
#define CTL_OUT_OFF 20004864ull
#define OVF_OUT_OFF 20013056ull
#define OUT_NEED    (OVF_OUT_OFF + 131072ull)

#define PNT_WS_OFF   0ull
#define SLOT_WS_OFF  32000000ull
#define RES_WS_OFF   40000000ull
#define ROVF_WS_OFF  50002432ull
#define WS_NEED      (ROVF_WS_OFF + 65536ull)

// ---------------------------------------------------------------------------
// Shared per-point voxel math — bit-identical to the R3..R12 passing kernels.
// ---------------------------------------------------------------------------
__device__ __forceinline__ void voxel_hash_d(float px, float py, float pz,
                                             int& hw, unsigned& dbits)
{
#pragma clang fp contract(off)
    float fx = floorf(px * RINV);
    float fy = floorf(py * RINV);
    float fz = floorf(pz * RINV);

    long long gx = (long long)fx;
    long long gy = (long long)fy;
    long long gz = (long long)fz;
    long long s = gx * 73856093LL + gy * 19349669LL + gz * 83492791LL;
    long long h = s % (long long)BUFSZ;           // trunc, sign of dividend
    hw = (int)(h < 0 ? h + BUFSZ : h);

    float cx = (fx + 0.5f) * RESF;
    float cy = (fy + 0.5f) * RESF;
    float cz = (fz + 0.5f) * RESF;
    float dx = px - cx;
    float dy = py - cy;
    float dz = pz - cz;
    float d = dx * dx + dy * dy + dz * dz;        // no fp contraction
    dbits = __float_as_uint(d);
}

// ===========================================================================
// K1 (heterogeneous grid):
//   blocks [0, bblocks)          : multisplit binning + point->slot map
//   blocks [bblocks, +PACKB)     : stream-pack {neural,ts} -> pnt
// Pack blocks run on CUs the 489 bin-blocks leave idle; pack's 64 MB stream
// rides under the bin blocks' LDS-atomic phase (R12 lesson, block-granular).
// Disjoint outputs: {e64, ctl, ovfA, slot32} vs {pnt}. No races.
// ===========================================================================
__global__ __launch_bounds__(256) void bin_pack2(
    const float* __restrict__ points,
    unsigned long long* __restrict__ e64,
    unsigned int* __restrict__ ctl,
    unsigned long long* __restrict__ ovfA,
    unsigned int* __restrict__ slot32,
    const float* __restrict__ neural,
    const int* __restrict__ ts_upd,
    float4* __restrict__ pnt,
    int N, int M, int bblocks)
{
    int t = threadIdx.x;
    int b = blockIdx.x;

    if (b >= bblocks) {
        // ---- role: streaming pack ----
        int pb = b - bblocks;
        int T = PACKB * 256;
        for (int j = pb * 256 + t; j < M; j += T)
            pnt[j] = make_float4(neural[3 * j], neural[3 * j + 1],
                                 neural[3 * j + 2], __int_as_float(ts_upd[j]));
        return;
    }

    // ---- role: multisplit binning ----
    __shared__ unsigned int cnt[NBINS];
    for (int x = t; x < NBINS; x += 256) cnt[x] = 0;
    __syncthreads();

    int base = b * (256 * 16);
    unsigned hwv[16];
    unsigned dbv[16];

#pragma unroll
    for (int k = 0; k < 16; ++k) {
        int i = base + t + k * 256;
        hwv[k] = 0xFFFFFFFFu;                      // sentinel: i >= N
        dbv[k] = 0;
        if (i < N) {
            int hw; unsigned db;
            voxel_hash_d(points[3 * i], points[3 * i + 1], points[3 * i + 2],
                         hw, db);
            hwv[k] = (unsigned)hw;
            dbv[k] = db;
            if (db <= 0x3FFFFFFFu)
                atomicAdd(&cnt[hw >> BIN_SHIFT], 1u);
        }
    }
    __syncthreads();

    // reserve global ranges; cnt[x] becomes the block's running global cursor
    for (int x = t; x < NBINS; x += 256) {
        unsigned c = cnt[x];
        cnt[x] = c ? atomicAdd(&ctl[x], c) : 0u;
    }
    __syncthreads();

#pragma unroll
    for (int k = 0; k < 16; ++k) {
        if (hwv[k] == 0xFFFFFFFFu) continue;
        int i = base + t + k * 256;
        unsigned hw = hwv[k], db = dbv[k];
        if (db <= 0x3FFFFFFFu) {
            unsigned bin = hw >> BIN_SHIFT;
            unsigned idx = atomicAdd(&cnt[bin], 1u);
            if (idx < BIN_CAP) {
                unsigned slot = bin * BIN_CAP + idx;
                e64[slot] = ((unsigned long long)db << BIN_SHIFT)
                          | (hw & (BKT_PER_BIN - 1));
                slot32[i] = slot;
                continue;
            }
        }
        unsigned o = atomicAdd(&ctl[NBINS], 1u);
        unsigned oc = (o < OVF_CAP) ? o : (OVF_CAP - 1);
        if (o < OVF_CAP)
            ovfA[o] = ((unsigned long long)db << 24) | hw;   // hw < 2^24
        slot32[i] = 0x80000000u | oc;
    }
}

// ===========================================================================
// K2 (heterogeneous grid):
//   blocks [0, NBINS) : per-bin LDS segment-min -> res32 (dense writes)
//   block  NBINS      : exact ovf drain -> res_ovf (statistically empty)
// Pure windowed streaming now that the pack moved to K1.
// ===========================================================================
__global__ __launch_bounds__(256) void min_res2(
    const unsigned long long* __restrict__ e64,
    const unsigned int* __restrict__ ctl,
    const unsigned long long* __restrict__ ovfA,
    const int* __restrict__ bufidx,
    unsigned int* __restrict__ res32,
    unsigned int* __restrict__ res_ovf)
{
    __shared__ unsigned int tbl[BKT_PER_BIN];      // 32 KB
    int t = threadIdx.x;
    int b = blockIdx.x;

    if (b == NBINS) {
        // ---- role: exact overflow drain (statistically empty) ----
        unsigned ovfn = ctl[NBINS];
        if (ovfn > OVF_CAP) ovfn = OVF_CAP;
        for (unsigned o = t; o < ovfn; o += 256) {
            unsigned long long va = ovfA[o];
            unsigned hw = (unsigned)(va & 0xFFFFFFu);
            unsigned db = (unsigned)(va >> 24);
            unsigned bin = hw >> BIN_SHIFT;
            unsigned lb  = hw & (BKT_PER_BIN - 1);

            unsigned mn = 0xFFFFFFFFu;
            unsigned c = ctl[bin];
            if (c > BIN_CAP) c = BIN_CAP;
            const unsigned long long* e = e64 + (size_t)bin * BIN_CAP;
            for (unsigned j = 0; j < c; ++j) {
                unsigned long long v = e[j];
                if ((unsigned)(v & (BKT_PER_BIN - 1)) == lb) {
                    unsigned d2 = (unsigned)(v >> BIN_SHIFT);
                    if (d2 < mn) mn = d2;
                }
            }
            for (unsigned o2 = 0; o2 < ovfn; ++o2) {
                unsigned long long v2 = ovfA[o2];
                if ((unsigned)(v2 & 0xFFFFFFu) == hw) {
                    unsigned d2 = (unsigned)(v2 >> 24);
                    if (d2 < mn) mn = d2;
                }
            }
            bool keep = db <= mn;
            int hidx = bufidx[hw];
            res_ovf[o] = (keep ? 0x80000000u : 0u) | (unsigned)(hidx + 1);
        }
        return;
    }

    // ---- role: per-bin LDS segment-min + dense result records ----
    uint4* t4 = (uint4*)tbl;
    for (int l = t; l < BKT_PER_BIN / 4; l += 256)
        t4[l] = make_uint4(0xFFFFFFFFu, 0xFFFFFFFFu, 0xFFFFFFFFu, 0xFFFFFFFFu);
    __syncthreads();

    unsigned c = ctl[b];
    if (c > BIN_CAP) c = BIN_CAP;                  // excess went to ovf
    size_t ebase = (size_t)b * BIN_CAP;
    for (unsigned j = t; j < c; j += 256) {
        unsigned long long v = e64[ebase + j];
        atomicMin(&tbl[(unsigned)(v & (BKT_PER_BIN - 1))],
                  (unsigned)(v >> BIN_SHIFT));
    }

    unsigned ovfn = ctl[NBINS];
    if (ovfn > OVF_CAP) ovfn = OVF_CAP;
    unsigned gbase = (unsigned)b << BIN_SHIFT;
    for (unsigned o = t; o < ovfn; o += 256) {     // statistically empty
        unsigned long long va = ovfA[o];
        unsigned hw = (unsigned)(va & 0xFFFFFFu);
        if ((hw >> BIN_SHIFT) == (unsigned)b)
            atomicMin(&tbl[hw & (BKT_PER_BIN - 1)], (unsigned)(va >> 24));
    }
    __syncthreads();

    for (unsigned j = t; j < c; j += 256) {
        unsigned long long v = e64[ebase + j];
        unsigned lb = (unsigned)(v & (BKT_PER_BIN - 1));
        unsigned db = (unsigned)(v >> BIN_SHIFT);

        bool keep = db <= tbl[lb];
        int hidx = bufidx[gbase + lb];             // 32 KB window -> L2-hot
        res32[ebase + j] = (keep ? 0x80000000u : 0u) | (unsigned)(hidx + 1);
    }
}

// ===========================================================================
// K3: output pass — slot32 (dense) -> res32 (random 4B) -> pnt (random 16B).
// Within ~8% of the random-line-fill roofline (composed model R11). Unchanged.
// ===========================================================================
__global__ __launch_bounds__(256) void pass_out_S4(
    const float* __restrict__ points,
    const unsigned int* __restrict__ slot32,
    const unsigned int* __restrict__ res32,
    const unsigned int* __restrict__ res_ovf,
    const float4* __restrict__ pnt,
    const float* __restrict__ travel,
    const int* __restrict__ cur_ts_p,
    float* __restrict__ out,
    int N, int M, int S)               // S = ceil(N/4)
{
#pragma clang fp contract(off)
    int tid = blockIdx.x * 256 + threadIdx.x;
    if (tid >= S) return;

    float tcur = travel[cur_ts_p[0]];

    int      iv[4];
    bool     val[4];
    float    pxv[4], pyv[4], pzv[4];
    unsigned sv[4];

#pragma unroll
    for (int k = 0; k < 4; ++k) {
        int i = tid + k * S;
        val[k] = (i < N);
        iv[k]  = val[k] ? i : 0;
        pxv[k] = points[3 * iv[k] + 0];
        pyv[k] = points[3 * iv[k] + 1];
        pzv[k] = points[3 * iv[k] + 2];
        sv[k]  = slot32[iv[k]];
    }

    unsigned rv[4];
#pragma unroll
    for (int k = 0; k < 4; ++k) {
        const unsigned* rp = (sv[k] & 0x80000000u)
                           ? (res_ovf + (sv[k] & 0x7FFFFFFFu))
                           : (res32 + sv[k]);
        rv[k] = *rp;                                // 1 random 4B gather
    }

    int hidxv[4], idxwv[4];
    float4 ntv[4];
#pragma unroll
    for (int k = 0; k < 4; ++k) {
        hidxv[k] = (int)(rv[k] & 0x7FFFFFFFu) - 1;  // -1 == empty
        idxwv[k] = (hidxv[k] < 0) ? (hidxv[k] + M) : hidxv[k];
    }
#pragma unroll
    for (int k = 0; k < 4; ++k) ntv[k] = pnt[idxwv[k]];  // 1 random 16B gather

#pragma unroll
    for (int k = 0; k < 4; ++k) {
        if (!val[k]) continue;

        bool keep = (rv[k] >> 31) != 0u;

        float vx = ntv[k].x - pxv[k];
        float vy = ntv[k].y - pyv[k];
        float vz = ntv[k].z - pzv[k];
        float dist2 = vx * vx + vy * vy + vz * vz;  // no contraction

        int ts = __float_as_int(ntv[k].w);
        float dtv = tcur - travel[ts];

        const float THR = (float)(3.0 * 0.3 * 0.3);
        bool upd = keep && ((hidxv[k] == -1) || (dist2 > THR) || (dtv > 120.0f));

        out[iv[k]]         = dist2;
        out[N + iv[k]]     = dtv;
        out[2 * N + iv[k]] = upd ? 1.0f : 0.0f;
    }
}

// ===========================================================================
// Tier C fallback (proven in R3): used only if ws/out don't fit the fast path.
// ===========================================================================
__global__ __launch_bounds__(256) void pass_min_C(
    const float* __restrict__ points, unsigned int* __restrict__ seg, int N)
{
    int i = blockIdx.x * 256 + threadIdx.x;
    if (i >= N) return;
    int hw; unsigned dbits;
    voxel_hash_d(points[3 * i], points[3 * i + 1], points[3 * i + 2], hw, dbits);
    atomicMin(seg + hw, dbits);
}

__global__ __launch_bounds__(256) void pass_out_C(
    const float* __restrict__ points, const float* __restrict__ neural,
    const int* __restrict__ bufidx, const float* __restrict__ travel,
    const int* __restrict__ ts_upd, const int* __restrict__ cur_ts_p,
    const unsigned int* __restrict__ seg, float* __restrict__ out, int N, int M)
{
#pragma clang fp contract(off)
    int i = blockIdx.x * 256 + threadIdx.x;
    if (i >= N) return;
    float px = points[3 * i], py = points[3 * i + 1], pz = points[3 * i + 2];
    int hw; unsigned dbits;
    voxel_hash_d(px, py, pz, hw, dbits);
    bool keep = dbits <= seg[hw];
    int hidx = bufidx[hw];
    int idxw = (hidx < 0) ? (hidx + M) : hidx;
    float vx = neural[3 * idxw] - px;
    float vy = neural[3 * idxw + 1] - py;
    float vz = neural[3 * idxw + 2] - pz;
    float dist2 = vx * vx + vy * vy + vz * vz;
    int ts = ts_upd[idxw];
    float dtv = travel[cur_ts_p[0]] - travel[ts];
    const float THR = (float)(3.0 * 0.3 * 0.3);
    bool upd = keep && ((hidx == -1) || (dist2 > THR) || (dtv > 120.0f));
    out[i] = dist2;
    out[N + i] = dtv;
    out[2 * N + i] = upd ? 1.0f : 0.0f;
}

extern "C" void kernel_launch(void* const* d_in, const int* in_sizes, int n_in,
                              void* d_out, int out_size, void* d_ws, size_t ws_size,
                              hipStream_t stream)
{
    const float* points  = (const float*)d_in[0];
    const float* neural  = (const float*)d_in[1];
    const int*   bufidx  = (const int*)d_in[2];
    const float* travel  = (const float*)d_in[3];
    const int*   ts_upd  = (const int*)d_in[4];
    const int*   cur_ts  = (const int*)d_in[5];

    int N = in_sizes[0] / 3;
    int M = in_sizes[1] / 3;

    if (ws_size >= WS_NEED && (size_t)out_size * 4 >= OUT_NEED
        && N <= 2100000 && (size_t)N * 4 <= (RES_WS_OFF - SLOT_WS_OFF)) {
        char* ws = (char*)d_ws;
        char* ob = (char*)d_out;
        float4*             pnt     = (float4*)(ws + PNT_WS_OFF);
        unsigned int*       slot32  = (unsigned int*)(ws + SLOT_WS_OFF);
        unsigned int*       res32   = (unsigned int*)(ws + RES_WS_OFF);
        unsigned int*       res_ovf = (unsigned int*)(ws + ROVF_WS_OFF);
        unsigned long long* e64     = (unsigned long long*)(ob + E64_OUT_OFF);
        unsigned int*       ctl     = (unsigned int*)(ob + CTL_OUT_OFF);
        unsigned long long* ovfA    = (unsigned long long*)(ob + OVF_OUT_OFF);

        hipMemsetAsync(ctl, 0, 8192, stream);

        int bblocks = (N + 4095) / 4096;
        bin_pack2<<<bblocks + PACKB, 256, 0, stream>>>(
            points, e64, ctl, ovfA, slot32, neural, ts_upd, pnt, N, M, bblocks);
        min_res2<<<NBINS + 1, 256, 0, stream>>>(e64, ctl, ovfA, bufidx,
                                                res32, res_ovf);

        int S = (N + 3) / 4;
        int oblocks = (S + 255) / 256;
        pass_out_S4<<<oblocks, 256, 0, stream>>>(points, slot32, res32, res_ovf,
                                                 pnt, travel, cur_ts,
                                                 (float*)d_out, N, M, S);
    } else {
        unsigned int* seg = (unsigned int*)d_ws;                  // 40 MB
        hipMemsetAsync(seg, 0xFF, (size_t)BUFSZ * sizeof(unsigned int), stream);
        int pblocks = (N + 255) / 256;
        pass_min_C<<<pblocks, 256, 0, stream>>>(points, seg, N);
        pass_out_C<<<pblocks, 256, 0, stream>>>(points, neural, bufidx, travel,
                                                ts_upd, cur_ts, seg,
                                                (float*)d_out, N, M);
    }
}

// Round 15
// 139.610 us; speedup vs baseline: 1.8332x; 1.0059x over previous
//
#include <hip/hip_runtime.h>

#define BUFSZ 10000000
#define RESF 0.3f
// XLA canonicalizes x / const -> x * (1/const); 1.0f/0.3f folds to 0x40555555.
#define RINV (1.0f / 0.3f)

// ---- binning geometry -----------------------------------------------------
#define BIN_SHIFT   13
#define BKT_PER_BIN 8192                   // buckets per bin (32 KB LDS table)
#define NBINS       1221                   // ceil(10M / 8192)
#define BIN_CAP     2048                   // slots/bin (mean 1638 @ N=2M)
#define NSLOTS      (NBINS * BIN_CAP)      // 2,500,608
#define OVF_CAP     16384
#define PACKB       2048                   // streaming pack blocks in K1 grid

// ---- scratch layout -------------------------------------------------------
// d_out as scratch (24 MB, fully rewritten by pass_out_S4):
//   [0, 20,004,864)        e64  u64[NSLOTS]  {db(30)<<13 | lbkt(13)}
//   [20,004,864, +8KB)     ctl  u32[NBINS] counts + [NBINS] = ovf count
//   [20,013,056, +128KB)   ovfA u64[OVF_CAP] {db<<24 | hw}
// ws (proven >= 112 MB):
//   [0, 32M)               pnt     float4[2M] {x,y,z,ts}
//   [32M, 40M)             slot32  u32[N]  (point -> slot, 0x8000_0000|o = ovf)
//   [40M, 50,002,432)      res32   u32[NSLOTS] {keep<<31 | (hidx+1)}
//   [50,002,432, +64KB)    res_ovf u32[OVF_CAP]
#define E64_OUT_OFF 0ull
#define CTL_OUT_OFF 20004864ull
#define OVF_OUT_OFF 20013056ull
#define OUT_NEED    (OVF_OUT_OFF + 131072ull)

#define PNT_WS_OFF   0ull
#define SLOT_WS_OFF  32000000ull
#define RES_WS_OFF   40000000ull
#define ROVF_WS_OFF  50002432ull
#define WS_NEED      (ROVF_WS_OFF + 65536ull)

typedef float fvec4 __attribute__((ext_vector_type(4)));   // NT-store-legal 16B

// ---------------------------------------------------------------------------
// Shared per-point voxel math — bit-identical to the R3..R13 passing kernels.
// ---------------------------------------------------------------------------
__device__ __forceinline__ void voxel_hash_d(float px, float py, float pz,
                                             int& hw, unsigned& dbits)
{
#pragma clang fp contract(off)
    float fx = floorf(px * RINV);
    float fy = floorf(py * RINV);
    float fz = floorf(pz * RINV);

    long long gx = (long long)fx;
    long long gy = (long long)fy;
    long long gz = (long long)fz;
    long long s = gx * 73856093LL + gy * 19349669LL + gz * 83492791LL;
    long long h = s % (long long)BUFSZ;           // trunc, sign of dividend
    hw = (int)(h < 0 ? h + BUFSZ : h);

    float cx = (fx + 0.5f) * RESF;
    float cy = (fy + 0.5f) * RESF;
    float cz = (fz + 0.5f) * RESF;
    float dx = px - cx;
    float dy = py - cy;
    float dz = pz - cz;
    float d = dx * dx + dy * dy + dz * dz;        // no fp contraction
    dbits = __float_as_uint(d);
}

// ===========================================================================
// K1 (heterogeneous grid):
//   blocks [0, bblocks)      : multisplit binning + point->slot map
//   blocks [bblocks, +PACKB) : stream-pack {neural,ts} -> pnt  (NONTEMPORAL)
// The pack role uses nontemporal loads/stores so its ~104 MB stream does NOT
// evict the bin role's partially-filled e64 lines from L2 (R13 post-mortem:
// that eviction forced fill-on-write RMWs and stretched the bin role 30->67).
// Disjoint outputs: {e64, ctl, ovfA, slot32} vs {pnt}. No races.
// ===========================================================================
__global__ __launch_bounds__(256) void bin_pack2(
    const float* __restrict__ points,
    unsigned long long* __restrict__ e64,
    unsigned int* __restrict__ ctl,
    unsigned long long* __restrict__ ovfA,
    unsigned int* __restrict__ slot32,
    const float* __restrict__ neural,
    const int* __restrict__ ts_upd,
    float4* __restrict__ pnt,
    int N, int M, int bblocks)
{
    int t = threadIdx.x;
    int b = blockIdx.x;

    if (b >= bblocks) {
        // ---- role: streaming pack (nontemporal: bypass L2 retention) ----
        int pb = b - bblocks;
        int T = PACKB * 256;
        for (int j = pb * 256 + t; j < M; j += T) {
            float nx = __builtin_nontemporal_load(&neural[3 * j + 0]);
            float ny = __builtin_nontemporal_load(&neural[3 * j + 1]);
            float nz = __builtin_nontemporal_load(&neural[3 * j + 2]);
            int   tv = __builtin_nontemporal_load(&ts_upd[j]);
            fvec4 v;
            v.x = nx; v.y = ny; v.z = nz; v.w = __int_as_float(tv);
            __builtin_nontemporal_store(v, (fvec4*)&pnt[j]);
        }
        return;
    }

    // ---- role: multisplit binning ----
    __shared__ unsigned int cnt[NBINS];
    for (int x = t; x < NBINS; x += 256) cnt[x] = 0;
    __syncthreads();

    int base = b * (256 * 16);
    unsigned hwv[16];
    unsigned dbv[16];

#pragma unroll
    for (int k = 0; k < 16; ++k) {
        int i = base + t + k * 256;
        hwv[k] = 0xFFFFFFFFu;                      // sentinel: i >= N
        dbv[k] = 0;
        if (i < N) {
            int hw; unsigned db;
            voxel_hash_d(points[3 * i], points[3 * i + 1], points[3 * i + 2],
                         hw, db);
            hwv[k] = (unsigned)hw;
            dbv[k] = db;
            if (db <= 0x3FFFFFFFu)
                atomicAdd(&cnt[hw >> BIN_SHIFT], 1u);
        }
    }
    __syncthreads();

    // reserve global ranges; cnt[x] becomes the block's running global cursor
    for (int x = t; x < NBINS; x += 256) {
        unsigned c = cnt[x];
        cnt[x] = c ? atomicAdd(&ctl[x], c) : 0u;
    }
    __syncthreads();

#pragma unroll
    for (int k = 0; k < 16; ++k) {
        if (hwv[k] == 0xFFFFFFFFu) continue;
        int i = base + t + k * 256;
        unsigned hw = hwv[k], db = dbv[k];
        if (db <= 0x3FFFFFFFu) {
            unsigned bin = hw >> BIN_SHIFT;
            unsigned idx = atomicAdd(&cnt[bin], 1u);
            if (idx < BIN_CAP) {
                unsigned slot = bin * BIN_CAP + idx;
                e64[slot] = ((unsigned long long)db << BIN_SHIFT)
                          | (hw & (BKT_PER_BIN - 1));
                slot32[i] = slot;
                continue;
            }
        }
        unsigned o = atomicAdd(&ctl[NBINS], 1u);
        unsigned oc = (o < OVF_CAP) ? o : (OVF_CAP - 1);
        if (o < OVF_CAP)
            ovfA[o] = ((unsigned long long)db << 24) | hw;   // hw < 2^24
        slot32[i] = 0x80000000u | oc;
    }
}

// ===========================================================================
// K2 (heterogeneous grid):
//   blocks [0, NBINS) : per-bin LDS segment-min -> res32 (dense writes)
//   block  NBINS      : exact ovf drain -> res_ovf (statistically empty)
// ===========================================================================
__global__ __launch_bounds__(256) void min_res2(
    const unsigned long long* __restrict__ e64,
    const unsigned int* __restrict__ ctl,
    const unsigned long long* __restrict__ ovfA,
    const int* __restrict__ bufidx,
    unsigned int* __restrict__ res32,
    unsigned int* __restrict__ res_ovf)
{
    __shared__ unsigned int tbl[BKT_PER_BIN];      // 32 KB
    int t = threadIdx.x;
    int b = blockIdx.x;

    if (b == NBINS) {
        // ---- role: exact overflow drain (statistically empty) ----
        unsigned ovfn = ctl[NBINS];
        if (ovfn > OVF_CAP) ovfn = OVF_CAP;
        for (unsigned o = t; o < ovfn; o += 256) {
            unsigned long long va = ovfA[o];
            unsigned hw = (unsigned)(va & 0xFFFFFFu);
            unsigned db = (unsigned)(va >> 24);
            unsigned bin = hw >> BIN_SHIFT;
            unsigned lb  = hw & (BKT_PER_BIN - 1);

            unsigned mn = 0xFFFFFFFFu;
            unsigned c = ctl[bin];
            if (c > BIN_CAP) c = BIN_CAP;
            const unsigned long long* e = e64 + (size_t)bin * BIN_CAP;
            for (unsigned j = 0; j < c; ++j) {
                unsigned long long v = e[j];
                if ((unsigned)(v & (BKT_PER_BIN - 1)) == lb) {
                    unsigned d2 = (unsigned)(v >> BIN_SHIFT);
                    if (d2 < mn) mn = d2;
                }
            }
            for (unsigned o2 = 0; o2 < ovfn; ++o2) {
                unsigned long long v2 = ovfA[o2];
                if ((unsigned)(v2 & 0xFFFFFFu) == hw) {
                    unsigned d2 = (unsigned)(v2 >> 24);
                    if (d2 < mn) mn = d2;
                }
            }
            bool keep = db <= mn;
            int hidx = bufidx[hw];
            res_ovf[o] = (keep ? 0x80000000u : 0u) | (unsigned)(hidx + 1);
        }
        return;
    }

    // ---- role: per-bin LDS segment-min + dense result records ----
    uint4* t4 = (uint4*)tbl;
    for (int l = t; l < BKT_PER_BIN / 4; l += 256)
        t4[l] = make_uint4(0xFFFFFFFFu, 0xFFFFFFFFu, 0xFFFFFFFFu, 0xFFFFFFFFu);
    __syncthreads();

    unsigned c = ctl[b];
    if (c > BIN_CAP) c = BIN_CAP;                  // excess went to ovf
    size_t ebase = (size_t)b * BIN_CAP;
    for (unsigned j = t; j < c; j += 256) {
        unsigned long long v = e64[ebase + j];
        atomicMin(&tbl[(unsigned)(v & (BKT_PER_BIN - 1))],
                  (unsigned)(v >> BIN_SHIFT));
    }

    unsigned ovfn = ctl[NBINS];
    if (ovfn > OVF_CAP) ovfn = OVF_CAP;
    unsigned gbase = (unsigned)b << BIN_SHIFT;
    for (unsigned o = t; o < ovfn; o += 256) {     // statistically empty
        unsigned long long va = ovfA[o];
        unsigned hw = (unsigned)(va & 0xFFFFFFu);
        if ((hw >> BIN_SHIFT) == (unsigned)b)
            atomicMin(&tbl[hw & (BKT_PER_BIN - 1)], (unsigned)(va >> 24));
    }
    __syncthreads();

    for (unsigned j = t; j < c; j += 256) {
        unsigned long long v = e64[ebase + j];
        unsigned lb = (unsigned)(v & (BKT_PER_BIN - 1));
        unsigned db = (unsigned)(v >> BIN_SHIFT);

        bool keep = db <= tbl[lb];
        int hidx = bufidx[gbase + lb];             // 32 KB window -> L2-hot
        res32[ebase + j] = (keep ? 0x80000000u : 0u) | (unsigned)(hidx + 1);
    }
}

// ===========================================================================
// K3: output pass — slot32 (dense) -> res32 (random 4B) -> pnt (random 16B).
// Within ~8% of the random-line-fill roofline (composed model R11). Unchanged.
// ===========================================================================
__global__ __launch_bounds__(256) void pass_out_S4(
    const float* __restrict__ points,
    const unsigned int* __restrict__ slot32,
    const unsigned int* __restrict__ res32,
    const unsigned int* __restrict__ res_ovf,
    const float4* __restrict__ pnt,
    const float* __restrict__ travel,
    const int* __restrict__ cur_ts_p,
    float* __restrict__ out,
    int N, int M, int S)               // S = ceil(N/4)
{
#pragma clang fp contract(off)
    int tid = blockIdx.x * 256 + threadIdx.x;
    if (tid >= S) return;

    float tcur = travel[cur_ts_p[0]];

    int      iv[4];
    bool     val[4];
    float    pxv[4], pyv[4], pzv[4];
    unsigned sv[4];

#pragma unroll
    for (int k = 0; k < 4; ++k) {
        int i = tid + k * S;
        val[k] = (i < N);
        iv[k]  = val[k] ? i : 0;
        pxv[k] = points[3 * iv[k] + 0];
        pyv[k] = points[3 * iv[k] + 1];
        pzv[k] = points[3 * iv[k] + 2];
        sv[k]  = slot32[iv[k]];
    }

    unsigned rv[4];
#pragma unroll
    for (int k = 0; k < 4; ++k) {
        const unsigned* rp = (sv[k] & 0x80000000u)
                           ? (res_ovf + (sv[k] & 0x7FFFFFFFu))
                           : (res32 + sv[k]);
        rv[k] = *rp;                                // 1 random 4B gather
    }

    int hidxv[4], idxwv[4];
    float4 ntv[4];
#pragma unroll
    for (int k = 0; k < 4; ++k) {
        hidxv[k] = (int)(rv[k] & 0x7FFFFFFFu) - 1;  // -1 == empty
        idxwv[k] = (hidxv[k] < 0) ? (hidxv[k] + M) : hidxv[k];
    }
#pragma unroll
    for (int k = 0; k < 4; ++k) ntv[k] = pnt[idxwv[k]];  // 1 random 16B gather

#pragma unroll
    for (int k = 0; k < 4; ++k) {
        if (!val[k]) continue;

        bool keep = (rv[k] >> 31) != 0u;

        float vx = ntv[k].x - pxv[k];
        float vy = ntv[k].y - pyv[k];
        float vz = ntv[k].z - pzv[k];
        float dist2 = vx * vx + vy * vy + vz * vz;  // no contraction

        int ts = __float_as_int(ntv[k].w);
        float dtv = tcur - travel[ts];

        const float THR = (float)(3.0 * 0.3 * 0.3);
        bool upd = keep && ((hidxv[k] == -1) || (dist2 > THR) || (dtv > 120.0f));

        out[iv[k]]         = dist2;
        out[N + iv[k]]     = dtv;
        out[2 * N + iv[k]] = upd ? 1.0f : 0.0f;
    }
}

// ===========================================================================
// Tier C fallback (proven in R3): used only if ws/out don't fit the fast path.
// ===========================================================================
__global__ __launch_bounds__(256) void pass_min_C(
    const float* __restrict__ points, unsigned int* __restrict__ seg, int N)
{
    int i = blockIdx.x * 256 + threadIdx.x;
    if (i >= N) return;
    int hw; unsigned dbits;
    voxel_hash_d(points[3 * i], points[3 * i + 1], points[3 * i + 2], hw, dbits);
    atomicMin(seg + hw, dbits);
}

__global__ __launch_bounds__(256) void pass_out_C(
    const float* __restrict__ points, const float* __restrict__ neural,
    const int* __restrict__ bufidx, const float* __restrict__ travel,
    const int* __restrict__ ts_upd, const int* __restrict__ cur_ts_p,
    const unsigned int* __restrict__ seg, float* __restrict__ out, int N, int M)
{
#pragma clang fp contract(off)
    int i = blockIdx.x * 256 + threadIdx.x;
    if (i >= N) return;
    float px = points[3 * i], py = points[3 * i + 1], pz = points[3 * i + 2];
    int hw; unsigned dbits;
    voxel_hash_d(px, py, pz, hw, dbits);
    bool keep = dbits <= seg[hw];
    int hidx = bufidx[hw];
    int idxw = (hidx < 0) ? (hidx + M) : hidx;
    float vx = neural[3 * idxw] - px;
    float vy = neural[3 * idxw + 1] - py;
    float vz = neural[3 * idxw + 2] - pz;
    float dist2 = vx * vx + vy * vy + vz * vz;
    int ts = ts_upd[idxw];
    float dtv = travel[cur_ts_p[0]] - travel[ts];
    const float THR = (float)(3.0 * 0.3 * 0.3);
    bool upd = keep && ((hidx == -1) || (dist2 > THR) || (dtv > 120.0f));
    out[i] = dist2;
    out[N + i] = dtv;
    out[2 * N + i] = upd ? 1.0f : 0.0f;
}

extern "C" void kernel_launch(void* const* d_in, const int* in_sizes, int n_in,
                              void* d_out, int out_size, void* d_ws, size_t ws_size,
                              hipStream_t stream)
{
    const float* points  = (const float*)d_in[0];
    const float* neural  = (const float*)d_in[1];
    const int*   bufidx  = (const int*)d_in[2];
    const float* travel  = (const float*)d_in[3];
    const int*   ts_upd  = (const int*)d_in[4];
    const int*   cur_ts  = (const int*)d_in[5];

    int N = in_sizes[0] / 3;
    int M = in_sizes[1] / 3;

    if (ws_size >= WS_NEED && (size_t)out_size * 4 >= OUT_NEED
        && N <= 2100000 && (size_t)N * 4 <= (RES_WS_OFF - SLOT_WS_OFF)) {
        char* ws = (char*)d_ws;
        char* ob = (char*)d_out;
        float4*             pnt     = (float4*)(ws + PNT_WS_OFF);
        unsigned int*       slot32  = (unsigned int*)(ws + SLOT_WS_OFF);
        unsigned int*       res32   = (unsigned int*)(ws + RES_WS_OFF);
        unsigned int*       res_ovf = (unsigned int*)(ws + ROVF_WS_OFF);
        unsigned long long* e64     = (unsigned long long*)(ob + E64_OUT_OFF);
        unsigned int*       ctl     = (unsigned int*)(ob + CTL_OUT_OFF);
        unsigned long long* ovfA    = (unsigned long long*)(ob + OVF_OUT_OFF);

        hipMemsetAsync(ctl, 0, 8192, stream);

        int bblocks = (N + 4095) / 4096;
        bin_pack2<<<bblocks + PACKB, 256, 0, stream>>>(
            points, e64, ctl, ovfA, slot32, neural, ts_upd, pnt, N, M, bblocks);
        min_res2<<<NBINS + 1, 256, 0, stream>>>(e64, ctl, ovfA, bufidx,
                                                res32, res_ovf);

        int S = (N + 3) / 4;
        int oblocks = (S + 255) / 256;
        pass_out_S4<<<oblocks, 256, 0, stream>>>(points, slot32, res32, res_ovf,
                                                 pnt, travel, cur_ts,
                                                 (float*)d_out, N, M, S);
    } else {
        unsigned int* seg = (unsigned int*)d_ws;                  // 40 MB
        hipMemsetAsync(seg, 0xFF, (size_t)BUFSZ * sizeof(unsigned int), stream);
        int pblocks = (N + 255) / 256;
        pass_min_C<<<pblocks, 256, 0, stream>>>(points, seg, N);
        pass_out_C<<<pblocks, 256, 0, stream>>>(points, neural, bufidx, travel,
                                                ts_upd, cur_ts, seg,
                                                (float*)d_out, N, M);
    }
}